// Round 1
// baseline (693.991 us; speedup 1.0000x reference)
//
#include <hip/hip_runtime.h>
#include <math.h>

#define HW    4096
#define B_    32
#define CIN   256
#define HID   128
#define A_    9
#define NCLS  20
#define ODIM  65
#define M_    4096
#define NBOX  64

// ---- output layout (floats) ----
#define PROP_SIZE (B_*A_*HW*4)             // 4,718,592
#define IOU_SIZE  ((size_t)B_*A_*HW*NBOX)  // 75,497,472
#define IOU_OFF   ((size_t)PROP_SIZE)
#define CONF_LOSS_OFF (IOU_OFF + IOU_SIZE) // 80,216,064
#define REG_LOSS_OFF  (CONF_LOSS_OFF + 1)
#define CLS_OFF       (CONF_LOSS_OFF + 2)

// ---- workspace layout (floats) ----
#define WS_W1T   0                          // 32768 (W1 transposed to [c][o])
#define WS_CONF  32768                      // B*A*HW raw conf
#define WS_OFF4  (WS_CONF + B_*A_*HW)       // B*A*HW float4 offsets (post-sigmoid on xy)
#define WS_CLS   (WS_OFF4 + B_*A_*HW*4)     // 20 planes of B*HW raw class scores

__global__ __launch_bounds__(256) void transpose_w1(const float* __restrict__ W1,
                                                    float* __restrict__ W1t) {
    int i = blockIdx.x * 256 + threadIdx.x;   // 32768 total, W1 is [o][c] = [128][256]
    int o = i >> 8, c = i & 255;
    W1t[c * HID + o] = W1[i];
}

__device__ __forceinline__ float sigmoidf_(float x) {
    return 1.0f / (1.0f + expf(-x));
}

// One thread per spatial position s in [0, B*HW). Fused conv1+leaky+conv2+epilogue.
__global__ __launch_bounds__(256) void conv_fused(
    const float* __restrict__ features, const float* __restrict__ grid,
    const float* __restrict__ anc,      const float* __restrict__ b1v,
    const float* __restrict__ W2,       const float* __restrict__ b2v,
    float* __restrict__ ws,             float* __restrict__ dout)
{
    const int s  = blockIdx.x * 256 + threadIdx.x;   // grid = 512 blocks
    const int b  = s >> 12;
    const int hw = s & (HW - 1);

    const float* __restrict__ W1t = ws + WS_W1T;

    // ---- conv1: acc[o] = b1[o] + sum_c W1[o][c] * feat[b][c][hw] ----
    float acc[HID];
    {
        const float4* b14 = (const float4*)b1v;
        #pragma unroll
        for (int q = 0; q < HID / 4; ++q) {
            float4 v = b14[q];
            acc[4*q+0] = v.x; acc[4*q+1] = v.y; acc[4*q+2] = v.z; acc[4*q+3] = v.w;
        }
    }
    const float* fptr = features + (size_t)b * CIN * HW + hw;
    for (int c = 0; c < CIN; ++c) {
        float f = fptr[(size_t)c * HW];            // coalesced across lanes
        const float4* w4 = (const float4*)(W1t + c * HID);  // wave-uniform
        #pragma unroll
        for (int q = 0; q < HID / 4; ++q) {
            float4 wv = w4[q];
            acc[4*q+0] = fmaf(wv.x, f, acc[4*q+0]);
            acc[4*q+1] = fmaf(wv.y, f, acc[4*q+1]);
            acc[4*q+2] = fmaf(wv.z, f, acc[4*q+2]);
            acc[4*q+3] = fmaf(wv.w, f, acc[4*q+3]);
        }
    }
    // leaky relu (slope 0.01)
    #pragma unroll
    for (int o = 0; o < HID; ++o) acc[o] = acc[o] > 0.0f ? acc[o] : 0.01f * acc[o];

    // dot(W2 row, acc) with 4-way partial sums to break the dep chain
    #define DOT(row, OUTVAR)                                                  \
        {                                                                     \
            const float4* w4 = (const float4*)(W2 + (size_t)(row) * HID);     \
            float s0 = 0.f, s1 = 0.f, s2 = 0.f, s3 = 0.f;                     \
            _Pragma("unroll")                                                 \
            for (int q = 0; q < HID / 4; ++q) {                               \
                float4 wv = w4[q];                                            \
                s0 = fmaf(wv.x, acc[4*q+0], s0);                              \
                s1 = fmaf(wv.y, acc[4*q+1], s1);                              \
                s2 = fmaf(wv.z, acc[4*q+2], s2);                              \
                s3 = fmaf(wv.w, acc[4*q+3], s3);                              \
            }                                                                 \
            OUTVAR = ((s0 + s1) + (s2 + s3)) + b2v[row];                      \
        }

    // ---- conf channels [0,9): store raw for later sigmoid+loss ----
    for (int a = 0; a < A_; ++a) {
        float sum;
        DOT(a, sum);
        ws[WS_CONF + (size_t)(b * A_ + a) * HW + hw] = sum;
    }

    // ---- offset channels [9,45): sigmoid-0.5 on xy, store + proposals ----
    const float2 g2 = ((const float2*)grid)[s];
    const float gx = g2.x, gy = g2.y;
    for (int a = 0; a < A_; ++a) {
        float t0, t1, t2, t3;
        DOT(A_ + a * 4 + 0, t0);
        DOT(A_ + a * 4 + 1, t1);
        DOT(A_ + a * 4 + 2, t2);
        DOT(A_ + a * 4 + 3, t3);
        t0 = sigmoidf_(t0) - 0.5f;
        t1 = sigmoidf_(t1) - 0.5f;
        size_t idx = (size_t)(b * A_ + a) * HW + hw;
        float4 offv = make_float4(t0, t1, t2, t3);
        ((float4*)(ws + WS_OFF4))[idx] = offv;

        float aw = anc[2 * a], ah = anc[2 * a + 1];
        float xc = gx + t0, yc = gy + t1;
        float ww = aw * expf(t2), hh = ah * expf(t3);
        float4 prop = make_float4(xc - 0.5f * ww, yc - 0.5f * hh,
                                  xc + 0.5f * ww, yc + 0.5f * hh);
        ((float4*)dout)[idx] = prop;
    }

    // ---- class channels [45,65): store planes [c][b*HW+hw] ----
    for (int c = 0; c < NCLS; ++c) {
        float sum;
        DOT(5 * A_ + c, sum);
        ws[WS_CLS + (size_t)c * (B_ * HW) + s] = sum;
    }
    #undef DOT
}

// One wave per (b, a, 128-hw chunk); lane = bbox index n. Writes 256B/store, coalesced.
__global__ __launch_bounds__(256) void iou_kernel(
    const float* __restrict__ grid, const float* __restrict__ anc,
    const float* __restrict__ bboxes, float* __restrict__ dout)
{
    const int CHUNK  = 128;
    const int nchunk = HW / CHUNK;                       // 32
    int wid  = (blockIdx.x * 256 + threadIdx.x) >> 6;    // 9216 waves total
    int lane = threadIdx.x & 63;
    int b    = wid / (A_ * nchunk);
    int rem  = wid % (A_ * nchunk);
    int a    = rem / nchunk;
    int hw0  = (rem % nchunk) * CHUNK;

    const float* bb = bboxes + ((size_t)b * NBOX + lane) * 5;
    float bx0 = bb[0], by0 = bb[1], bx2 = bb[2], by2 = bb[3];
    float area_b = (bx2 - bx0) * (by2 - by0);

    float hwd = 0.5f * anc[2 * a], hh = 0.5f * anc[2 * a + 1];
    float area_p = 4.0f * hwd * hh;

    float* outp = dout + IOU_OFF + (size_t)(b * A_ + a) * HW * NBOX;
    const float2* gp = (const float2*)(grid + (size_t)b * HW * 2);
    for (int hw = hw0; hw < hw0 + CHUNK; ++hw) {
        float2 g = gp[hw];                               // wave-uniform
        float px0 = g.x - hwd, px2 = g.x + hwd;
        float py0 = g.y - hh,  py2 = g.y + hh;
        float dx = fmaxf(fminf(bx2, px2) - fmaxf(bx0, px0), 0.0f);
        float dy = fmaxf(fminf(by2, py2) - fmaxf(by0, py0), 0.0f);
        float inter = dx * dy;
        outp[(size_t)hw * NBOX + lane] = inter / (area_p + area_b - inter);
    }
}

// class_scores gather: out[m*20+c] = cls_plane[c][spatial(pos_idx[m])]
__global__ __launch_bounds__(256) void cls_gather(
    const float* __restrict__ ws, const int* __restrict__ pos_idx,
    float* __restrict__ dout)
{
    int t = blockIdx.x * 256 + threadIdx.x;              // 81920 total
    if (t >= M_ * NCLS) return;
    int m = t / NCLS, c = t % NCLS;
    int ip = pos_idx[m];
    int bb = ip / (A_ * HW);
    int hw = ip & (HW - 1);
    dout[CLS_OFF + t] = ws[WS_CLS + (size_t)c * (B_ * HW) + bb * HW + hw];
}

// single block: conf + reg losses
__global__ __launch_bounds__(1024) void loss_kernel(
    const float* __restrict__ ws, const float* __restrict__ GT_offsets,
    const int* __restrict__ pos_idx, const int* __restrict__ neg_idx,
    float* __restrict__ dout)
{
    int tid = threadIdx.x;
    float conf_sum = 0.0f, reg_sum = 0.0f;
    for (int m = tid; m < M_; m += 1024) {
        int ip = pos_idx[m], in_ = neg_idx[m];
        float cp = sigmoidf_(ws[WS_CONF + ip]);
        float cn = sigmoidf_(ws[WS_CONF + in_]);
        conf_sum += (cp - 1.0f) * (cp - 1.0f) + cn * cn;
        float4 off = ((const float4*)(ws + WS_OFF4))[ip];
        float d0 = off.x - GT_offsets[4 * m + 0];
        float d1 = off.y - GT_offsets[4 * m + 1];
        float d2 = off.z - GT_offsets[4 * m + 2];
        float d3 = off.w - GT_offsets[4 * m + 3];
        reg_sum += d0 * d0 + d1 * d1 + d2 * d2 + d3 * d3;
    }
    #pragma unroll
    for (int off = 32; off > 0; off >>= 1) {
        conf_sum += __shfl_down(conf_sum, off);
        reg_sum  += __shfl_down(reg_sum, off);
    }
    __shared__ float rc[16], rr[16];
    int w = tid >> 6;
    if ((tid & 63) == 0) { rc[w] = conf_sum; rr[w] = reg_sum; }
    __syncthreads();
    if (tid == 0) {
        float c = 0.0f, r = 0.0f;
        #pragma unroll
        for (int i = 0; i < 16; ++i) { c += rc[i]; r += rr[i]; }
        dout[CONF_LOSS_OFF] = c / (2.0f * M_);
        dout[REG_LOSS_OFF]  = r / (float)M_;
    }
}

extern "C" void kernel_launch(void* const* d_in, const int* in_sizes, int n_in,
                              void* d_out, int out_size, void* d_ws, size_t ws_size,
                              hipStream_t stream) {
    const float* features    = (const float*)d_in[0];
    const float* grid        = (const float*)d_in[1];
    const float* anc         = (const float*)d_in[2];
    const float* bboxes      = (const float*)d_in[3];
    const float* GT_offsets  = (const float*)d_in[4];
    // d_in[5] = GT_conf_scores: only its shape matters in the reference
    const float* W1          = (const float*)d_in[6];
    const float* b1          = (const float*)d_in[7];
    const float* W2          = (const float*)d_in[8];
    const float* b2          = (const float*)d_in[9];
    const int*   pos_idx     = (const int*)d_in[10];
    const int*   neg_idx     = (const int*)d_in[11];
    float* out = (float*)d_out;
    float* ws  = (float*)d_ws;

    transpose_w1<<<128, 256, 0, stream>>>(W1, ws + WS_W1T);
    conv_fused<<<(B_ * HW) / 256, 256, 0, stream>>>(features, grid, anc, b1, W2, b2, ws, out);
    iou_kernel<<<(B_ * A_ * (HW / 128)) / 4, 256, 0, stream>>>(grid, anc, bboxes, out);
    cls_gather<<<(M_ * NCLS + 255) / 256, 256, 0, stream>>>(ws, pos_idx, out);
    loss_kernel<<<1, 1024, 0, stream>>>(ws, GT_offsets, pos_idx, neg_idx, out);
}

// Round 2
// 185.887 us; speedup vs baseline: 3.7334x; 3.7334x over previous
//
#include <hip/hip_runtime.h>
#include <math.h>

typedef __attribute__((ext_vector_type(8))) short short8;
typedef __attribute__((ext_vector_type(4))) float f32x4;

#define HW    4096
#define B_    32
#define CIN   256
#define HID   128
#define A_    9
#define NCLS  20
#define M_    4096
#define NBOX  64
#define S_TOT (B_*HW)

// ---- output layout (floats) ----
#define PROP_SIZE (B_*A_*HW*4)
#define IOU_OFF   ((size_t)PROP_SIZE)
#define IOU_SIZE  ((size_t)B_*A_*HW*NBOX)
#define CONF_LOSS_OFF (IOU_OFF + IOU_SIZE)
#define REG_LOSS_OFF  (CONF_LOSS_OFF + 1)
#define CLS_OFF       (CONF_LOSS_OFF + 2)

// ---- workspace layout (float offsets) ----
#define WS_W1A_F 0                          // 32768 ushort (W1 in A-frag order)
#define WS_W2A_F 16384                      // 10240 ushort (W2 padded to 80 rows, A-frag order)
#define WS_B2P   21504                      // 80 floats (b2 padded)
#define WS_CONF  21632                      // B*A*HW raw conf
#define WS_OFF4  (WS_CONF + B_*A_*HW)       // B*A*HW float4 offsets
#define WS_CLS   (WS_OFF4 + B_*A_*HW*4)    // 20 planes of B*HW raw class scores

__device__ __forceinline__ unsigned short f2bf(float x) {   // RNE float->bf16
    unsigned int u = __float_as_uint(x);
    unsigned int r = (u + 0x7FFFu + ((u >> 16) & 1u)) >> 16;
    return (unsigned short)r;
}
__device__ __forceinline__ float sigmoidf_(float x) { return 1.0f / (1.0f + expf(-x)); }

// LDS byte addr for FbT[col][k] (col<64, k<256, bf16), XOR-swizzled, b128-aligned
__device__ __forceinline__ int fbt_addr(int col, int k) {
    return col * 512 + ((k * 2) ^ ((col & 31) << 4));
}
// LDS byte addr for HbT[col][k] (col<64, k<128, bf16) at base+32768
__device__ __forceinline__ int hbt_addr(int col, int k) {
    return 32768 + col * 256 + ((k * 2) ^ ((col & 7) << 4));
}

// Pack W1 (128x256) and W2 (65x128 -> 80x128 zero-pad) into MFMA A-fragment order.
// A-frag for 16x16x32: lane l holds A[m*16 + (l&15)][ks*32 + (l>>4)*8 + j], j=0..7.
__global__ __launch_bounds__(256) void prep_weights(
    const float* __restrict__ W1, const float* __restrict__ W2,
    const float* __restrict__ b2, float* __restrict__ ws)
{
    int t = blockIdx.x * 256 + threadIdx.x;
    unsigned short* W1a = (unsigned short*)(ws + WS_W1A_F);
    unsigned short* W2a = (unsigned short*)(ws + WS_W2A_F);
    if (t < 32768) {
        int j = t & 7, l = (t >> 3) & 63, ks = (t >> 9) & 7, m = t >> 12;
        int row = m * 16 + (l & 15);
        int k   = ks * 32 + (l >> 4) * 8 + j;
        W1a[t] = f2bf(W1[row * CIN + k]);
    } else if (t < 32768 + 10240) {
        int u = t - 32768;
        int j = u & 7, l = (u >> 3) & 63, ks = (u >> 9) & 3, m = u >> 11;
        int row = m * 16 + (l & 15);
        int k   = ks * 32 + (l >> 4) * 8 + j;
        W2a[u] = f2bf(row < 65 ? W2[row * HID + k] : 0.0f);
    } else if (t < 32768 + 10240 + 80) {
        int v = t - 43008;
        ws[WS_B2P + v] = (v < 65) ? b2[v] : 0.0f;
    }
}

// One block = 64 spatial positions. Fused: stage F -> GEMM1(W1) -> leaky ->
// GEMM2(W2) -> epilogue (conf/offsets/proposals/cls).
__global__ __launch_bounds__(256) void conv_mfma(
    const float* __restrict__ features, const float* __restrict__ grid,
    const float* __restrict__ anc,      const float* __restrict__ b1,
    float* __restrict__ ws,             float* __restrict__ dout)
{
    __shared__ __align__(16) char smem[49152];   // FbT 32KB | HbT 16KB; Ot reuses FbT

    const int tid = threadIdx.x;
    const int s0  = blockIdx.x * 64;
    const int b   = s0 >> 12;
    const int hw0 = s0 & (HW - 1);
    const int col = tid & 63;
    const int wv  = tid >> 6;          // wave id 0..3
    const int ln  = tid & 63;
    const int kg  = ln >> 4;           // k-group 0..3
    const int colg = wv * 16 + (ln & 15);

    // ---- stage F tile (256 x 64) fp32 -> bf16 -> swizzled LDS transposed ----
    {
        const float* fbase = features + (size_t)b * CIN * HW + hw0 + col;
        #pragma unroll
        for (int cc = 0; cc < 8; ++cc) {
            int k0 = wv * 64 + cc * 8;
            unsigned int pk[4];
            #pragma unroll
            for (int r = 0; r < 4; ++r) {
                float x0 = fbase[(size_t)(k0 + 2 * r)     * HW];
                float x1 = fbase[(size_t)(k0 + 2 * r + 1) * HW];
                pk[r] = (unsigned int)f2bf(x0) | ((unsigned int)f2bf(x1) << 16);
            }
            *(uint4*)(smem + fbt_addr(col, k0)) = make_uint4(pk[0], pk[1], pk[2], pk[3]);
        }
    }
    __syncthreads();

    // ---- GEMM1: hdn[128][64] = W1 @ F. Wave owns 16 cols, all 128 rows. ----
    const unsigned short* W1a = (const unsigned short*)(ws + WS_W1A_F);
    f32x4 acc[8];
    #pragma unroll
    for (int m = 0; m < 8; ++m) acc[m] = (f32x4){0.f, 0.f, 0.f, 0.f};
    #pragma unroll
    for (int ks = 0; ks < 8; ++ks) {
        short8 bf = *(const short8*)(smem + fbt_addr(colg, ks * 32 + kg * 8));
        #pragma unroll
        for (int m = 0; m < 8; ++m) {
            short8 af = *(const short8*)(W1a + ((m * 8 + ks) * 64 + ln) * 8);
            acc[m] = __builtin_amdgcn_mfma_f32_16x16x32_bf16(af, bf, acc[m], 0, 0, 0);
        }
    }

    // ---- bias + leaky relu, bf16, write HbT (swizzled) ----
    #pragma unroll
    for (int m = 0; m < 8; ++m) {
        float4 bv = *(const float4*)(b1 + m * 16 + kg * 4);
        float v0 = acc[m][0] + bv.x, v1 = acc[m][1] + bv.y;
        float v2 = acc[m][2] + bv.z, v3 = acc[m][3] + bv.w;
        v0 = v0 > 0.f ? v0 : 0.01f * v0;  v1 = v1 > 0.f ? v1 : 0.01f * v1;
        v2 = v2 > 0.f ? v2 : 0.01f * v2;  v3 = v3 > 0.f ? v3 : 0.01f * v3;
        unsigned int lo = (unsigned int)f2bf(v0) | ((unsigned int)f2bf(v1) << 16);
        unsigned int hi = (unsigned int)f2bf(v2) | ((unsigned int)f2bf(v3) << 16);
        *(uint2*)(smem + hbt_addr(colg, m * 16 + kg * 4)) = make_uint2(lo, hi);
    }
    __syncthreads();

    // ---- GEMM2: out[80][64] = W2pad @ hdn ----
    const unsigned short* W2a = (const unsigned short*)(ws + WS_W2A_F);
    f32x4 a2[5];
    #pragma unroll
    for (int m = 0; m < 5; ++m) a2[m] = (f32x4){0.f, 0.f, 0.f, 0.f};
    #pragma unroll
    for (int ks = 0; ks < 4; ++ks) {
        short8 bf = *(const short8*)(smem + hbt_addr(colg, ks * 32 + kg * 8));
        #pragma unroll
        for (int m = 0; m < 5; ++m) {
            short8 af = *(const short8*)(W2a + ((m * 4 + ks) * 64 + ln) * 8);
            a2[m] = __builtin_amdgcn_mfma_f32_16x16x32_bf16(af, bf, a2[m], 0, 0, 0);
        }
    }

    // ---- stage out tile to LDS (fp32, stride 65 to avoid bank conflicts) ----
    float* Ot = (float*)smem;            // reuses FbT region (all reads done)
    const float* b2p = ws + WS_B2P;
    #pragma unroll
    for (int m = 0; m < 5; ++m) {
        float4 bv = *(const float4*)(b2p + m * 16 + kg * 4);
        #pragma unroll
        for (int i = 0; i < 4; ++i)
            Ot[(m * 16 + kg * 4 + i) * 65 + colg] = a2[m][i] + ((const float*)&bv)[i];
    }
    __syncthreads();

    // ---- epilogue: wave 0 conf, waves 1-2 offsets+proposals, wave 3 cls ----
    const float* OtC = (const float*)smem;
    const int hw = hw0 + col;
    if (wv == 0) {
        #pragma unroll
        for (int a = 0; a < A_; ++a)
            ws[WS_CONF + (size_t)(b * A_ + a) * HW + hw] = OtC[a * 65 + col];
    } else if (wv == 3) {
        #pragma unroll
        for (int c = 0; c < NCLS; ++c)
            ws[WS_CLS + (size_t)c * S_TOT + b * HW + hw] = OtC[(45 + c) * 65 + col];
    } else {
        const float2 g2 = ((const float2*)grid)[(size_t)b * HW + hw];
        int a0 = (wv == 1) ? 0 : 4;
        int a1 = (wv == 1) ? 4 : 9;
        for (int a = a0; a < a1; ++a) {
            float t0 = OtC[(A_ + 4 * a + 0) * 65 + col];
            float t1 = OtC[(A_ + 4 * a + 1) * 65 + col];
            float t2 = OtC[(A_ + 4 * a + 2) * 65 + col];
            float t3 = OtC[(A_ + 4 * a + 3) * 65 + col];
            t0 = sigmoidf_(t0) - 0.5f;
            t1 = sigmoidf_(t1) - 0.5f;
            size_t idx = (size_t)(b * A_ + a) * HW + hw;
            ((float4*)(ws + WS_OFF4))[idx] = make_float4(t0, t1, t2, t3);
            float aw = anc[2 * a], ah = anc[2 * a + 1];
            float xc = g2.x + t0, yc = g2.y + t1;
            float wn = aw * expf(t2), hn = ah * expf(t3);
            ((float4*)dout)[idx] = make_float4(xc - 0.5f * wn, yc - 0.5f * hn,
                                               xc + 0.5f * wn, yc + 0.5f * hn);
        }
    }
}

// One wave per (b, a, 128-hw chunk); lane = bbox index n. 256B coalesced stores.
__global__ __launch_bounds__(256) void iou_kernel(
    const float* __restrict__ grid, const float* __restrict__ anc,
    const float* __restrict__ bboxes, float* __restrict__ dout)
{
    const int CHUNK  = 128;
    const int nchunk = HW / CHUNK;
    int wid  = (blockIdx.x * 256 + threadIdx.x) >> 6;
    int lane = threadIdx.x & 63;
    int b    = wid / (A_ * nchunk);
    int rem  = wid % (A_ * nchunk);
    int a    = rem / nchunk;
    int hw0  = (rem % nchunk) * CHUNK;

    const float* bb = bboxes + ((size_t)b * NBOX + lane) * 5;
    float bx0 = bb[0], by0 = bb[1], bx2 = bb[2], by2 = bb[3];
    float area_b = (bx2 - bx0) * (by2 - by0);

    float hwd = 0.5f * anc[2 * a], hh = 0.5f * anc[2 * a + 1];
    float area_p = 4.0f * hwd * hh;

    float* outp = dout + IOU_OFF + (size_t)(b * A_ + a) * HW * NBOX;
    const float2* gp = (const float2*)(grid + (size_t)b * HW * 2);
    for (int hw = hw0; hw < hw0 + CHUNK; ++hw) {
        float2 g = gp[hw];
        float px0 = g.x - hwd, px2 = g.x + hwd;
        float py0 = g.y - hh,  py2 = g.y + hh;
        float dx = fmaxf(fminf(bx2, px2) - fmaxf(bx0, px0), 0.0f);
        float dy = fmaxf(fminf(by2, py2) - fmaxf(by0, py0), 0.0f);
        float inter = dx * dy;
        outp[(size_t)hw * NBOX + lane] = inter / (area_p + area_b - inter);
    }
}

__global__ __launch_bounds__(256) void cls_gather(
    const float* __restrict__ ws, const int* __restrict__ pos_idx,
    float* __restrict__ dout)
{
    int t = blockIdx.x * 256 + threadIdx.x;
    if (t >= M_ * NCLS) return;
    int m = t / NCLS, c = t % NCLS;
    int ip = pos_idx[m];
    int bb = ip / (A_ * HW);
    int hw = ip & (HW - 1);
    dout[CLS_OFF + t] = ws[WS_CLS + (size_t)c * S_TOT + bb * HW + hw];
}

__global__ __launch_bounds__(1024) void loss_kernel(
    const float* __restrict__ ws, const float* __restrict__ GT_offsets,
    const int* __restrict__ pos_idx, const int* __restrict__ neg_idx,
    float* __restrict__ dout)
{
    int tid = threadIdx.x;
    float conf_sum = 0.0f, reg_sum = 0.0f;
    for (int m = tid; m < M_; m += 1024) {
        int ip = pos_idx[m], in_ = neg_idx[m];
        float cp = sigmoidf_(ws[WS_CONF + ip]);
        float cn = sigmoidf_(ws[WS_CONF + in_]);
        conf_sum += (cp - 1.0f) * (cp - 1.0f) + cn * cn;
        float4 off = ((const float4*)(ws + WS_OFF4))[ip];
        float d0 = off.x - GT_offsets[4 * m + 0];
        float d1 = off.y - GT_offsets[4 * m + 1];
        float d2 = off.z - GT_offsets[4 * m + 2];
        float d3 = off.w - GT_offsets[4 * m + 3];
        reg_sum += d0 * d0 + d1 * d1 + d2 * d2 + d3 * d3;
    }
    #pragma unroll
    for (int off = 32; off > 0; off >>= 1) {
        conf_sum += __shfl_down(conf_sum, off);
        reg_sum  += __shfl_down(reg_sum, off);
    }
    __shared__ float rc[16], rr[16];
    int w = tid >> 6;
    if ((tid & 63) == 0) { rc[w] = conf_sum; rr[w] = reg_sum; }
    __syncthreads();
    if (tid == 0) {
        float c = 0.0f, r = 0.0f;
        #pragma unroll
        for (int i = 0; i < 16; ++i) { c += rc[i]; r += rr[i]; }
        dout[CONF_LOSS_OFF] = c / (2.0f * M_);
        dout[REG_LOSS_OFF]  = r / (float)M_;
    }
}

extern "C" void kernel_launch(void* const* d_in, const int* in_sizes, int n_in,
                              void* d_out, int out_size, void* d_ws, size_t ws_size,
                              hipStream_t stream) {
    const float* features    = (const float*)d_in[0];
    const float* grid        = (const float*)d_in[1];
    const float* anc         = (const float*)d_in[2];
    const float* bboxes      = (const float*)d_in[3];
    const float* GT_offsets  = (const float*)d_in[4];
    const float* W1          = (const float*)d_in[6];
    const float* b1          = (const float*)d_in[7];
    const float* W2          = (const float*)d_in[8];
    const float* b2          = (const float*)d_in[9];
    const int*   pos_idx     = (const int*)d_in[10];
    const int*   neg_idx     = (const int*)d_in[11];
    float* out = (float*)d_out;
    float* ws  = (float*)d_ws;

    prep_weights<<<169, 256, 0, stream>>>(W1, W2, b2, ws);
    conv_mfma<<<S_TOT / 64, 256, 0, stream>>>(features, grid, anc, b1, ws, out);
    iou_kernel<<<(B_ * A_ * (HW / 128)) / 4, 256, 0, stream>>>(grid, anc, bboxes, out);
    cls_gather<<<(M_ * NCLS + 255) / 256, 256, 0, stream>>>(ws, pos_idx, out);
    loss_kernel<<<1, 1024, 0, stream>>>(ws, GT_offsets, pos_idx, neg_idx, out);
}

// Round 3
// 172.211 us; speedup vs baseline: 4.0299x; 1.0794x over previous
//
#include <hip/hip_runtime.h>
#include <math.h>

typedef __attribute__((ext_vector_type(8))) short short8;
typedef __attribute__((ext_vector_type(4))) float f32x4;

#define HW    4096
#define B_    32
#define CIN   256
#define HID   128
#define A_    9
#define NCLS  20
#define M_    4096
#define NBOX  64
#define S_TOT (B_*HW)

// ---- output layout (floats) ----
#define PROP_SIZE (B_*A_*HW*4)
#define IOU_OFF   ((size_t)PROP_SIZE)
#define IOU_SIZE  ((size_t)B_*A_*HW*NBOX)
#define CONF_LOSS_OFF (IOU_OFF + IOU_SIZE)
#define REG_LOSS_OFF  (CONF_LOSS_OFF + 1)
#define CLS_OFF       (CONF_LOSS_OFF + 2)

// ---- workspace layout (float offsets) ----
#define WS_W1A_F 0                          // 32768 ushort (W1 in A-frag order)
#define WS_W2A_F 16384                      // 10240 ushort (W2 padded to 80 rows)
#define WS_B2P   21504                      // 80 floats (b2 padded)
#define WS_CONF  21632                      // B*A*HW raw conf
#define WS_OFF4  (WS_CONF + B_*A_*HW)       // B*A*HW float4 offsets
#define WS_CLS   (WS_OFF4 + B_*A_*HW*4)     // 20 planes of B*HW raw class scores

__device__ __forceinline__ unsigned short f2bf(float x) {   // RNE float->bf16
    unsigned int u = __float_as_uint(x);
    unsigned int r = (u + 0x7FFFu + ((u >> 16) & 1u)) >> 16;
    return (unsigned short)r;
}
__device__ __forceinline__ float sigmoidf_(float x) { return 1.0f / (1.0f + expf(-x)); }

// LDS byte addr for FbT[col][k] (col<64, k<256, bf16), XOR-swizzled, b128-aligned
__device__ __forceinline__ int fbt_addr(int col, int k) {
    return col * 512 + ((k * 2) ^ ((col & 31) << 4));
}
// LDS byte addr for HbT[col][k] (col<64, k<128, bf16) at base+32768
__device__ __forceinline__ int hbt_addr(int col, int k) {
    return 32768 + col * 256 + ((k * 2) ^ ((col & 7) << 4));
}

// Pack W1 (128x256) and W2 (65x128 -> 80x128 zero-pad) into MFMA A-fragment order.
// A-frag for 16x16x32: lane l holds A[m*16 + (l&15)][ks*32 + (l>>4)*8 + j], j=0..7.
__global__ __launch_bounds__(256) void prep_weights(
    const float* __restrict__ W1, const float* __restrict__ W2,
    const float* __restrict__ b2, float* __restrict__ ws)
{
    int t = blockIdx.x * 256 + threadIdx.x;
    unsigned short* W1a = (unsigned short*)(ws + WS_W1A_F);
    unsigned short* W2a = (unsigned short*)(ws + WS_W2A_F);
    if (t < 32768) {
        int j = t & 7, l = (t >> 3) & 63, ks = (t >> 9) & 7, m = t >> 12;
        int row = m * 16 + (l & 15);
        int k   = ks * 32 + (l >> 4) * 8 + j;
        W1a[t] = f2bf(W1[row * CIN + k]);
    } else if (t < 32768 + 10240) {
        int u = t - 32768;
        int j = u & 7, l = (u >> 3) & 63, ks = (u >> 9) & 3, m = u >> 11;
        int row = m * 16 + (l & 15);
        int k   = ks * 32 + (l >> 4) * 8 + j;
        W2a[u] = f2bf(row < 65 ? W2[row * HID + k] : 0.0f);
    } else if (t < 32768 + 10240 + 80) {
        int v = t - 43008;
        ws[WS_B2P + v] = (v < 65) ? b2[v] : 0.0f;
    }
}

// One block = 64 spatial positions of one batch b. Fused: stage F -> GEMM1(W1)
// -> leaky -> GEMM2(W2) -> IoU (independent, stores drain in background)
// -> epilogue (conf/offsets/proposals/cls).
__global__ __launch_bounds__(256, 3) void conv_mfma(
    const float* __restrict__ features, const float* __restrict__ grid,
    const float* __restrict__ anc,      const float* __restrict__ b1,
    const float* __restrict__ bboxes,
    float* __restrict__ ws,             float* __restrict__ dout)
{
    __shared__ __align__(16) char smem[49152];   // FbT 32KB | HbT 16KB; Ot reuses FbT

    const int tid = threadIdx.x;
    const int s0  = blockIdx.x * 64;
    const int b   = s0 >> 12;
    const int hw0 = s0 & (HW - 1);
    const int col = tid & 63;
    const int wv  = tid >> 6;          // wave id 0..3
    const int ln  = tid & 63;
    const int kg  = ln >> 4;           // k-group 0..3
    const int colg = wv * 16 + (ln & 15);

    // ---- stage F tile (256 x 64) fp32 -> bf16 -> swizzled LDS transposed ----
    {
        const float* fbase = features + (size_t)b * CIN * HW + hw0 + col;
        #pragma unroll
        for (int cc = 0; cc < 8; ++cc) {
            int k0 = wv * 64 + cc * 8;
            unsigned int pk[4];
            #pragma unroll
            for (int r = 0; r < 4; ++r) {
                float x0 = fbase[(size_t)(k0 + 2 * r)     * HW];
                float x1 = fbase[(size_t)(k0 + 2 * r + 1) * HW];
                pk[r] = (unsigned int)f2bf(x0) | ((unsigned int)f2bf(x1) << 16);
            }
            *(uint4*)(smem + fbt_addr(col, k0)) = make_uint4(pk[0], pk[1], pk[2], pk[3]);
        }
    }
    __syncthreads();

    // ---- GEMM1: hdn[128][64] = W1 @ F. Wave owns 16 cols, all 128 rows. ----
    const unsigned short* W1a = (const unsigned short*)(ws + WS_W1A_F);
    f32x4 acc[8];
    #pragma unroll
    for (int m = 0; m < 8; ++m) acc[m] = (f32x4){0.f, 0.f, 0.f, 0.f};
    #pragma unroll
    for (int ks = 0; ks < 8; ++ks) {
        short8 bf = *(const short8*)(smem + fbt_addr(colg, ks * 32 + kg * 8));
        #pragma unroll
        for (int m = 0; m < 8; ++m) {
            short8 af = *(const short8*)(W1a + ((m * 8 + ks) * 64 + ln) * 8);
            acc[m] = __builtin_amdgcn_mfma_f32_16x16x32_bf16(af, bf, acc[m], 0, 0, 0);
        }
    }

    // ---- bias + leaky relu, bf16, write HbT (swizzled) ----
    #pragma unroll
    for (int m = 0; m < 8; ++m) {
        float4 bv = *(const float4*)(b1 + m * 16 + kg * 4);
        float v0 = acc[m][0] + bv.x, v1 = acc[m][1] + bv.y;
        float v2 = acc[m][2] + bv.z, v3 = acc[m][3] + bv.w;
        v0 = v0 > 0.f ? v0 : 0.01f * v0;  v1 = v1 > 0.f ? v1 : 0.01f * v1;
        v2 = v2 > 0.f ? v2 : 0.01f * v2;  v3 = v3 > 0.f ? v3 : 0.01f * v3;
        unsigned int lo = (unsigned int)f2bf(v0) | ((unsigned int)f2bf(v1) << 16);
        unsigned int hi = (unsigned int)f2bf(v2) | ((unsigned int)f2bf(v3) << 16);
        *(uint2*)(smem + hbt_addr(colg, m * 16 + kg * 4)) = make_uint2(lo, hi);
    }
    __syncthreads();

    // ---- GEMM2: out[80][64] = W2pad @ hdn ----
    const unsigned short* W2a = (const unsigned short*)(ws + WS_W2A_F);
    f32x4 a2[5];
    #pragma unroll
    for (int m = 0; m < 5; ++m) a2[m] = (f32x4){0.f, 0.f, 0.f, 0.f};
    #pragma unroll
    for (int ks = 0; ks < 4; ++ks) {
        short8 bf = *(const short8*)(smem + hbt_addr(colg, ks * 32 + kg * 8));
        #pragma unroll
        for (int m = 0; m < 5; ++m) {
            short8 af = *(const short8*)(W2a + ((m * 4 + ks) * 64 + ln) * 8);
            a2[m] = __builtin_amdgcn_mfma_f32_16x16x32_bf16(af, bf, a2[m], 0, 0, 0);
        }
    }

    // ---- fused IoU (independent of conv): wave w owns 16 hw rows, lane = box n.
    // Stores are fire-and-forget; they drain during epilogue / other blocks' GEMMs.
    {
        const float* bb = bboxes + ((size_t)b * NBOX + ln) * 5;
        float bx0 = bb[0], by0 = bb[1], bx2 = bb[2], by2 = bb[3];
        float area_b = (bx2 - bx0) * (by2 - by0);
        const float2* gp = (const float2*)grid + (size_t)b * HW;
        #pragma unroll
        for (int a = 0; a < A_; ++a) {
            float hwd = 0.5f * anc[2 * a], hh = 0.5f * anc[2 * a + 1];
            float area_p = 4.0f * hwd * hh;
            float* outp = dout + IOU_OFF + (size_t)(b * A_ + a) * HW * NBOX;
            #pragma unroll 4
            for (int i = 0; i < 16; ++i) {
                int hw = hw0 + wv * 16 + i;
                float2 g = gp[hw];
                float px0 = g.x - hwd, px2 = g.x + hwd;
                float py0 = g.y - hh,  py2 = g.y + hh;
                float dx = fmaxf(fminf(bx2, px2) - fmaxf(bx0, px0), 0.0f);
                float dy = fmaxf(fminf(by2, py2) - fmaxf(by0, py0), 0.0f);
                float inter = dx * dy;
                outp[(size_t)hw * NBOX + ln] = inter / (area_p + area_b - inter);
            }
        }
    }

    // ---- stage out tile to LDS (fp32, stride 65 to avoid bank conflicts) ----
    float* Ot = (float*)smem;            // reuses FbT region (all reads done)
    const float* b2p = ws + WS_B2P;
    #pragma unroll
    for (int m = 0; m < 5; ++m) {
        float4 bv = *(const float4*)(b2p + m * 16 + kg * 4);
        #pragma unroll
        for (int i = 0; i < 4; ++i)
            Ot[(m * 16 + kg * 4 + i) * 65 + colg] = a2[m][i] + ((const float*)&bv)[i];
    }
    __syncthreads();

    // ---- epilogue: wave 0 conf, waves 1-2 offsets+proposals, wave 3 cls ----
    const float* OtC = (const float*)smem;
    const int hw = hw0 + col;
    if (wv == 0) {
        #pragma unroll
        for (int a = 0; a < A_; ++a)
            ws[WS_CONF + (size_t)(b * A_ + a) * HW + hw] = OtC[a * 65 + col];
    } else if (wv == 3) {
        #pragma unroll
        for (int c = 0; c < NCLS; ++c)
            ws[WS_CLS + (size_t)c * S_TOT + b * HW + hw] = OtC[(45 + c) * 65 + col];
    } else {
        const float2 g2 = ((const float2*)grid)[(size_t)b * HW + hw];
        int a0 = (wv == 1) ? 0 : 4;
        int a1 = (wv == 1) ? 4 : 9;
        for (int a = a0; a < a1; ++a) {
            float t0 = OtC[(A_ + 4 * a + 0) * 65 + col];
            float t1 = OtC[(A_ + 4 * a + 1) * 65 + col];
            float t2 = OtC[(A_ + 4 * a + 2) * 65 + col];
            float t3 = OtC[(A_ + 4 * a + 3) * 65 + col];
            t0 = sigmoidf_(t0) - 0.5f;
            t1 = sigmoidf_(t1) - 0.5f;
            size_t idx = (size_t)(b * A_ + a) * HW + hw;
            ((float4*)(ws + WS_OFF4))[idx] = make_float4(t0, t1, t2, t3);
            float aw = anc[2 * a], ah = anc[2 * a + 1];
            float xc = g2.x + t0, yc = g2.y + t1;
            float wn = aw * expf(t2), hn = ah * expf(t3);
            ((float4*)dout)[idx] = make_float4(xc - 0.5f * wn, yc - 0.5f * hn,
                                               xc + 0.5f * wn, yc + 0.5f * hn);
        }
    }
}

__global__ __launch_bounds__(256) void cls_gather(
    const float* __restrict__ ws, const int* __restrict__ pos_idx,
    float* __restrict__ dout)
{
    int t = blockIdx.x * 256 + threadIdx.x;
    if (t >= M_ * NCLS) return;
    int m = t / NCLS, c = t % NCLS;
    int ip = pos_idx[m];
    int bb = ip / (A_ * HW);
    int hw = ip & (HW - 1);
    dout[CLS_OFF + t] = ws[WS_CLS + (size_t)c * S_TOT + bb * HW + hw];
}

__global__ __launch_bounds__(1024) void loss_kernel(
    const float* __restrict__ ws, const float* __restrict__ GT_offsets,
    const int* __restrict__ pos_idx, const int* __restrict__ neg_idx,
    float* __restrict__ dout)
{
    int tid = threadIdx.x;
    float conf_sum = 0.0f, reg_sum = 0.0f;
    for (int m = tid; m < M_; m += 1024) {
        int ip = pos_idx[m], in_ = neg_idx[m];
        float cp = sigmoidf_(ws[WS_CONF + ip]);
        float cn = sigmoidf_(ws[WS_CONF + in_]);
        conf_sum += (cp - 1.0f) * (cp - 1.0f) + cn * cn;
        float4 off = ((const float4*)(ws + WS_OFF4))[ip];
        float d0 = off.x - GT_offsets[4 * m + 0];
        float d1 = off.y - GT_offsets[4 * m + 1];
        float d2 = off.z - GT_offsets[4 * m + 2];
        float d3 = off.w - GT_offsets[4 * m + 3];
        reg_sum += d0 * d0 + d1 * d1 + d2 * d2 + d3 * d3;
    }
    #pragma unroll
    for (int off = 32; off > 0; off >>= 1) {
        conf_sum += __shfl_down(conf_sum, off);
        reg_sum  += __shfl_down(reg_sum, off);
    }
    __shared__ float rc[16], rr[16];
    int w = tid >> 6;
    if ((tid & 63) == 0) { rc[w] = conf_sum; rr[w] = reg_sum; }
    __syncthreads();
    if (tid == 0) {
        float c = 0.0f, r = 0.0f;
        #pragma unroll
        for (int i = 0; i < 16; ++i) { c += rc[i]; r += rr[i]; }
        dout[CONF_LOSS_OFF] = c / (2.0f * M_);
        dout[REG_LOSS_OFF]  = r / (float)M_;
    }
}

extern "C" void kernel_launch(void* const* d_in, const int* in_sizes, int n_in,
                              void* d_out, int out_size, void* d_ws, size_t ws_size,
                              hipStream_t stream) {
    const float* features    = (const float*)d_in[0];
    const float* grid        = (const float*)d_in[1];
    const float* anc         = (const float*)d_in[2];
    const float* bboxes      = (const float*)d_in[3];
    const float* GT_offsets  = (const float*)d_in[4];
    const float* W1          = (const float*)d_in[6];
    const float* b1          = (const float*)d_in[7];
    const float* W2          = (const float*)d_in[8];
    const float* b2          = (const float*)d_in[9];
    const int*   pos_idx     = (const int*)d_in[10];
    const int*   neg_idx     = (const int*)d_in[11];
    float* out = (float*)d_out;
    float* ws  = (float*)d_ws;

    prep_weights<<<169, 256, 0, stream>>>(W1, W2, b2, ws);
    conv_mfma<<<S_TOT / 64, 256, 0, stream>>>(features, grid, anc, b1, bboxes, ws, out);
    cls_gather<<<(M_ * NCLS + 255) / 256, 256, 0, stream>>>(ws, pos_idx, out);
    loss_kernel<<<1, 1024, 0, stream>>>(ws, GT_offsets, pos_idx, neg_idx, out);
}

// Round 4
// 159.141 us; speedup vs baseline: 4.3609x; 1.0821x over previous
//
#include <hip/hip_runtime.h>
#include <math.h>

typedef __attribute__((ext_vector_type(8))) short short8;
typedef __attribute__((ext_vector_type(4))) float f32x4;

#define HW    4096
#define B_    32
#define CIN   256
#define HID   128
#define A_    9
#define NCLS  20
#define M_    4096
#define NBOX  64
#define S_TOT (B_*HW)

// ---- output layout (floats) ----
#define PROP_SIZE (B_*A_*HW*4)
#define IOU_OFF   ((size_t)PROP_SIZE)
#define IOU_SIZE  ((size_t)B_*A_*HW*NBOX)
#define CONF_LOSS_OFF (IOU_OFF + IOU_SIZE)
#define REG_LOSS_OFF  (CONF_LOSS_OFF + 1)
#define CLS_OFF       (CONF_LOSS_OFF + 2)

// ---- workspace layout (float offsets) ----
#define WS_W1A_F 0                          // 32768 ushort (W1, A-frag order [ks][m])
#define WS_W2A_F 16384                      // 10240 ushort (W2 padded to 80 rows, [ks][m])
#define WS_B2P   21504                      // 80 floats (b2 padded)
#define WS_CONF  21632                      // B*A*HW raw conf
#define WS_OFF4  (WS_CONF + B_*A_*HW)       // B*A*HW float4 offsets
#define WS_CLS   (WS_OFF4 + B_*A_*HW*4)     // 20 planes of B*HW raw class scores

__device__ __forceinline__ unsigned short f2bf(float x) {   // RNE float->bf16
    unsigned int u = __float_as_uint(x);
    unsigned int r = (u + 0x7FFFu + ((u >> 16) & 1u)) >> 16;
    return (unsigned short)r;
}
__device__ __forceinline__ float vrcp(float x) {            // v_rcp_f32, ~1ulp
    float r; asm("v_rcp_f32 %0, %1" : "=v"(r) : "v"(x)); return r;
}
__device__ __forceinline__ float vexp2(float x) {           // v_exp_f32 = 2^x
    float r; asm("v_exp_f32 %0, %1" : "=v"(r) : "v"(x)); return r;
}
__device__ __forceinline__ float fexp(float x)  { return vexp2(x * 1.44269504f); }
__device__ __forceinline__ float fsig(float x)  { return vrcp(1.0f + fexp(-x)); }

// LDS byte addr for FbT[col][k] (col<64, k<256, bf16), XOR-swizzled, b128-aligned
__device__ __forceinline__ int fbt_addr(int col, int k) {
    return col * 512 + ((k * 2) ^ ((col & 31) << 4));
}
// LDS byte addr for HbT[col][k] (col<64, k<128, bf16) at base+32768
__device__ __forceinline__ int hbt_addr(int col, int k) {
    return 32768 + col * 256 + ((k * 2) ^ ((col & 7) << 4));
}

// Pack W1 (128x256) and W2 (65x128 -> 80x128 zero-pad) into MFMA A-fragment order,
// fragment index = ks*NM + m (ks-major => all m-frags of one ks-step are an 8KB
// contiguous window; the 4 lock-stepped waves share it through L1).
// A-frag for 16x16x32: lane l holds A[m*16 + (l&15)][ks*32 + (l>>4)*8 + j], j=0..7.
__global__ __launch_bounds__(256) void prep_weights(
    const float* __restrict__ W1, const float* __restrict__ W2,
    const float* __restrict__ b2, float* __restrict__ ws)
{
    int t = blockIdx.x * 256 + threadIdx.x;
    unsigned short* W1a = (unsigned short*)(ws + WS_W1A_F);
    unsigned short* W2a = (unsigned short*)(ws + WS_W2A_F);
    if (t < 32768) {
        int j = t & 7, l = (t >> 3) & 63, f = t >> 9;   // f = ks*8 + m
        int ks = f >> 3, m = f & 7;
        int row = m * 16 + (l & 15);
        int k   = ks * 32 + (l >> 4) * 8 + j;
        W1a[t] = f2bf(W1[row * CIN + k]);
    } else if (t < 32768 + 10240) {
        int u = t - 32768;
        int j = u & 7, l = (u >> 3) & 63, f = u >> 9;   // f = ks*5 + m
        int ks = f / 5, m = f % 5;
        int row = m * 16 + (l & 15);
        int k   = ks * 32 + (l >> 4) * 8 + j;
        W2a[u] = f2bf(row < 65 ? W2[row * HID + k] : 0.0f);
    } else if (t < 32768 + 10240 + 80) {
        int v = t - 43008;
        ws[WS_B2P + v] = (v < 65) ? b2[v] : 0.0f;
    }
}

// One block = 64 spatial positions of one batch b. Fused: stage F -> GEMM1(W1)
// -> leaky -> GEMM2(W2) -> IoU (independent) -> epilogue.
__global__ __launch_bounds__(256, 3) void conv_mfma(
    const float* __restrict__ features, const float* __restrict__ grid,
    const float* __restrict__ anc,      const float* __restrict__ b1,
    const float* __restrict__ bboxes,
    float* __restrict__ ws,             float* __restrict__ dout)
{
    __shared__ __align__(16) char smem[49152];   // FbT 32KB | HbT 16KB; Ot reuses FbT

    const int tid = threadIdx.x;
    const int s0  = blockIdx.x * 64;
    const int b   = s0 >> 12;
    const int hw0 = s0 & (HW - 1);
    const int col = tid & 63;
    const int wv  = tid >> 6;          // wave id 0..3
    const int ln  = tid & 63;
    const int kg  = ln >> 4;           // k-group 0..3
    const int colg = wv * 16 + (ln & 15);

    // ---- stage F tile (256 x 64) fp32 -> bf16 -> swizzled LDS transposed ----
    {
        const float* fbase = features + (size_t)b * CIN * HW + hw0 + col;
        #pragma unroll
        for (int cc = 0; cc < 8; ++cc) {
            int k0 = wv * 64 + cc * 8;
            unsigned int pk[4];
            #pragma unroll
            for (int r = 0; r < 4; ++r) {
                float x0 = fbase[(size_t)(k0 + 2 * r)     * HW];
                float x1 = fbase[(size_t)(k0 + 2 * r + 1) * HW];
                pk[r] = (unsigned int)f2bf(x0) | ((unsigned int)f2bf(x1) << 16);
            }
            *(uint4*)(smem + fbt_addr(col, k0)) = make_uint4(pk[0], pk[1], pk[2], pk[3]);
        }
    }
    __syncthreads();

    // ---- GEMM1: hdn[128][64] = W1 @ F. Wave owns 16 cols, all 128 rows. ----
    const unsigned short* W1a = (const unsigned short*)(ws + WS_W1A_F);
    f32x4 acc[8];
    #pragma unroll
    for (int m = 0; m < 8; ++m) acc[m] = (f32x4){0.f, 0.f, 0.f, 0.f};
    #pragma unroll
    for (int ks = 0; ks < 8; ++ks) {
        short8 bf = *(const short8*)(smem + fbt_addr(colg, ks * 32 + kg * 8));
        #pragma unroll
        for (int m = 0; m < 8; ++m) {
            short8 af = *(const short8*)(W1a + ((ks * 8 + m) * 64 + ln) * 8);
            acc[m] = __builtin_amdgcn_mfma_f32_16x16x32_bf16(af, bf, acc[m], 0, 0, 0);
        }
    }

    // ---- bias + leaky relu, bf16, write HbT (swizzled) ----
    #pragma unroll
    for (int m = 0; m < 8; ++m) {
        float4 bv = *(const float4*)(b1 + m * 16 + kg * 4);
        float v0 = acc[m][0] + bv.x, v1 = acc[m][1] + bv.y;
        float v2 = acc[m][2] + bv.z, v3 = acc[m][3] + bv.w;
        v0 = v0 > 0.f ? v0 : 0.01f * v0;  v1 = v1 > 0.f ? v1 : 0.01f * v1;
        v2 = v2 > 0.f ? v2 : 0.01f * v2;  v3 = v3 > 0.f ? v3 : 0.01f * v3;
        unsigned int lo = (unsigned int)f2bf(v0) | ((unsigned int)f2bf(v1) << 16);
        unsigned int hi = (unsigned int)f2bf(v2) | ((unsigned int)f2bf(v3) << 16);
        *(uint2*)(smem + hbt_addr(colg, m * 16 + kg * 4)) = make_uint2(lo, hi);
    }
    __syncthreads();

    // ---- GEMM2: out[80][64] = W2pad @ hdn ----
    const unsigned short* W2a = (const unsigned short*)(ws + WS_W2A_F);
    f32x4 a2[5];
    #pragma unroll
    for (int m = 0; m < 5; ++m) a2[m] = (f32x4){0.f, 0.f, 0.f, 0.f};
    #pragma unroll
    for (int ks = 0; ks < 4; ++ks) {
        short8 bf = *(const short8*)(smem + hbt_addr(colg, ks * 32 + kg * 8));
        #pragma unroll
        for (int m = 0; m < 5; ++m) {
            short8 af = *(const short8*)(W2a + ((ks * 5 + m) * 64 + ln) * 8);
            a2[m] = __builtin_amdgcn_mfma_f32_16x16x32_bf16(af, bf, a2[m], 0, 0, 0);
        }
    }

    // ---- fused IoU: lane = (hwi 0..3, nq 0..15); each lane computes 4 boxes ->
    // float4 stores, wave writes 1KB contiguous. rcp instead of divide; box-edge
    // minus-grid shared across the 9 anchors.
    {
        const int hwi = ln >> 4;
        const int nq  = ln & 15;
        float bx0[4], by0[4], bx2[4], by2[4], areab[4];
        #pragma unroll
        for (int j = 0; j < 4; ++j) {
            const float* bb = bboxes + ((size_t)b * NBOX + nq * 4 + j) * 5;
            bx0[j] = bb[0]; by0[j] = bb[1]; bx2[j] = bb[2]; by2[j] = bb[3];
            areab[j] = (bx2[j] - bx0[j]) * (by2[j] - by0[j]);
        }
        float hwd_[A_], hh_[A_], ap_[A_];
        #pragma unroll
        for (int a = 0; a < A_; ++a) {
            hwd_[a] = 0.5f * anc[2 * a];
            hh_[a]  = 0.5f * anc[2 * a + 1];
            ap_[a]  = 4.0f * hwd_[a] * hh_[a];
        }
        const float2* gp = (const float2*)grid + (size_t)b * HW;
        float* ioub = dout + IOU_OFF + (size_t)b * A_ * HW * NBOX;
        for (int t = 0; t < 4; ++t) {
            int hw = hw0 + wv * 16 + t * 4 + hwi;
            float2 g = gp[hw];
            float e2x[4], e0x[4], e2y[4], e0y[4];
            #pragma unroll
            for (int j = 0; j < 4; ++j) {
                e2x[j] = bx2[j] - g.x;  e0x[j] = bx0[j] - g.x;
                e2y[j] = by2[j] - g.y;  e0y[j] = by0[j] - g.y;
            }
            #pragma unroll
            for (int a = 0; a < A_; ++a) {
                float hwd = hwd_[a], hh = hh_[a], ap = ap_[a];
                float res[4];
                #pragma unroll
                for (int j = 0; j < 4; ++j) {
                    float dx = fmaxf(fminf(e2x[j], hwd) - fmaxf(e0x[j], -hwd), 0.0f);
                    float dy = fmaxf(fminf(e2y[j], hh ) - fmaxf(e0y[j], -hh ), 0.0f);
                    float inter = dx * dy;
                    res[j] = inter * vrcp(ap + areab[j] - inter);
                }
                *(float4*)(ioub + ((size_t)a * HW + hw) * NBOX + nq * 4) =
                    make_float4(res[0], res[1], res[2], res[3]);
            }
        }
    }

    // ---- stage out tile to LDS (fp32, stride 65 to avoid bank conflicts) ----
    float* Ot = (float*)smem;            // reuses FbT region (all reads done)
    const float* b2p = ws + WS_B2P;
    #pragma unroll
    for (int m = 0; m < 5; ++m) {
        float4 bv = *(const float4*)(b2p + m * 16 + kg * 4);
        #pragma unroll
        for (int i = 0; i < 4; ++i)
            Ot[(m * 16 + kg * 4 + i) * 65 + colg] = a2[m][i] + ((const float*)&bv)[i];
    }
    __syncthreads();

    // ---- epilogue: wave 0 conf, waves 1-2 offsets+proposals, wave 3 cls ----
    const float* OtC = (const float*)smem;
    const int hw = hw0 + col;
    if (wv == 0) {
        #pragma unroll
        for (int a = 0; a < A_; ++a)
            ws[WS_CONF + (size_t)(b * A_ + a) * HW + hw] = OtC[a * 65 + col];
    } else if (wv == 3) {
        #pragma unroll
        for (int c = 0; c < NCLS; ++c)
            ws[WS_CLS + (size_t)c * S_TOT + b * HW + hw] = OtC[(45 + c) * 65 + col];
    } else {
        const float2 g2 = ((const float2*)grid)[(size_t)b * HW + hw];
        int a0 = (wv == 1) ? 0 : 4;
        int a1 = (wv == 1) ? 4 : 9;
        for (int a = a0; a < a1; ++a) {
            float t0 = OtC[(A_ + 4 * a + 0) * 65 + col];
            float t1 = OtC[(A_ + 4 * a + 1) * 65 + col];
            float t2 = OtC[(A_ + 4 * a + 2) * 65 + col];
            float t3 = OtC[(A_ + 4 * a + 3) * 65 + col];
            t0 = fsig(t0) - 0.5f;
            t1 = fsig(t1) - 0.5f;
            size_t idx = (size_t)(b * A_ + a) * HW + hw;
            ((float4*)(ws + WS_OFF4))[idx] = make_float4(t0, t1, t2, t3);
            float aw = anc[2 * a], ah = anc[2 * a + 1];
            float xc = g2.x + t0, yc = g2.y + t1;
            float wn = aw * fexp(t2), hn = ah * fexp(t3);
            ((float4*)dout)[idx] = make_float4(xc - 0.5f * wn, yc - 0.5f * hn,
                                               xc + 0.5f * wn, yc + 0.5f * hn);
        }
    }
}

// blocks [0,320): class_scores gather; block 320: conf+reg losses.
__global__ __launch_bounds__(256) void tail_kernel(
    const float* __restrict__ ws, const float* __restrict__ GT_offsets,
    const int* __restrict__ pos_idx, const int* __restrict__ neg_idx,
    float* __restrict__ dout)
{
    int tid = threadIdx.x;
    if (blockIdx.x < 320) {
        int t = blockIdx.x * 256 + tid;            // 81920 = 320*256 exactly
        int m = t / NCLS, c = t % NCLS;
        int ip = pos_idx[m];
        int bb = ip / (A_ * HW);
        int hw = ip & (HW - 1);
        dout[CLS_OFF + t] = ws[WS_CLS + (size_t)c * S_TOT + bb * HW + hw];
        return;
    }
    float conf_sum = 0.0f, reg_sum = 0.0f;
    for (int m = tid; m < M_; m += 256) {
        int ip = pos_idx[m], in_ = neg_idx[m];
        float cp = fsig(ws[WS_CONF + ip]);
        float cn = fsig(ws[WS_CONF + in_]);
        conf_sum += (cp - 1.0f) * (cp - 1.0f) + cn * cn;
        float4 off = ((const float4*)(ws + WS_OFF4))[ip];
        float d0 = off.x - GT_offsets[4 * m + 0];
        float d1 = off.y - GT_offsets[4 * m + 1];
        float d2 = off.z - GT_offsets[4 * m + 2];
        float d3 = off.w - GT_offsets[4 * m + 3];
        reg_sum += d0 * d0 + d1 * d1 + d2 * d2 + d3 * d3;
    }
    #pragma unroll
    for (int off = 32; off > 0; off >>= 1) {
        conf_sum += __shfl_down(conf_sum, off);
        reg_sum  += __shfl_down(reg_sum, off);
    }
    __shared__ float rc[4], rr[4];
    int w = tid >> 6;
    if ((tid & 63) == 0) { rc[w] = conf_sum; rr[w] = reg_sum; }
    __syncthreads();
    if (tid == 0) {
        float c = rc[0] + rc[1] + rc[2] + rc[3];
        float r = rr[0] + rr[1] + rr[2] + rr[3];
        dout[CONF_LOSS_OFF] = c / (2.0f * M_);
        dout[REG_LOSS_OFF]  = r / (float)M_;
    }
}

extern "C" void kernel_launch(void* const* d_in, const int* in_sizes, int n_in,
                              void* d_out, int out_size, void* d_ws, size_t ws_size,
                              hipStream_t stream) {
    const float* features    = (const float*)d_in[0];
    const float* grid        = (const float*)d_in[1];
    const float* anc         = (const float*)d_in[2];
    const float* bboxes      = (const float*)d_in[3];
    const float* GT_offsets  = (const float*)d_in[4];
    const float* W1          = (const float*)d_in[6];
    const float* b1          = (const float*)d_in[7];
    const float* W2          = (const float*)d_in[8];
    const float* b2          = (const float*)d_in[9];
    const int*   pos_idx     = (const int*)d_in[10];
    const int*   neg_idx     = (const int*)d_in[11];
    float* out = (float*)d_out;
    float* ws  = (float*)d_ws;

    prep_weights<<<169, 256, 0, stream>>>(W1, W2, b2, ws);
    conv_mfma<<<S_TOT / 64, 256, 0, stream>>>(features, grid, anc, b1, bboxes, ws, out);
    tail_kernel<<<321, 256, 0, stream>>>(ws, GT_offsets, pos_idx, neg_idx, out);
}

// Round 6
// 118.738 us; speedup vs baseline: 5.8447x; 1.3403x over previous
//
#include <hip/hip_runtime.h>
#include <math.h>

typedef __attribute__((ext_vector_type(8))) short short8;
typedef __attribute__((ext_vector_type(4))) float f32x4;

#define HW    4096
#define B_    32
#define CIN   256
#define HID   128
#define A_    9
#define NCLS  20
#define M_    4096
#define NBOX  64
#define S_TOT (B_*HW)

// ---- output layout (floats) ----
#define PROP_SIZE (B_*A_*HW*4)
#define IOU_OFF   ((size_t)PROP_SIZE)
#define IOU_SIZE  ((size_t)B_*A_*HW*NBOX)
#define CONF_LOSS_OFF (IOU_OFF + IOU_SIZE)
#define REG_LOSS_OFF  (CONF_LOSS_OFF + 1)
#define CLS_OFF       (CONF_LOSS_OFF + 2)

// ---- workspace layout (float offsets) ----
#define WS_W1A_F 0                          // 32768 ushort (W1, A-frag order [ks][m])
#define WS_W2A_F 16384                      // 10240 ushort (W2 padded to 80 rows, [ks][m])
#define WS_B2P   21504                      // 80 floats (b2 padded)
#define WS_CONF  21632                      // B*A*HW raw conf
#define WS_OFF4  (WS_CONF + B_*A_*HW)       // B*A*HW float4 offsets
#define WS_CLS   (WS_OFF4 + B_*A_*HW*4)     // 20 planes of B*HW raw class scores

__device__ __forceinline__ unsigned short f2bf(float x) {   // RNE float->bf16
    unsigned int u = __float_as_uint(x);
    unsigned int r = (u + 0x7FFFu + ((u >> 16) & 1u)) >> 16;
    return (unsigned short)r;
}
__device__ __forceinline__ float vrcp(float x) {            // v_rcp_f32, ~1ulp
    float r; asm("v_rcp_f32 %0, %1" : "=v"(r) : "v"(x)); return r;
}
__device__ __forceinline__ float vexp2(float x) {           // v_exp_f32 = 2^x
    float r; asm("v_exp_f32 %0, %1" : "=v"(r) : "v"(x)); return r;
}
__device__ __forceinline__ float fexp(float x)  { return vexp2(x * 1.44269504f); }
__device__ __forceinline__ float fsig(float x)  { return vrcp(1.0f + fexp(-x)); }

// LDS byte addr for FbT[col][k] (col<64, k<256, bf16), XOR-swizzled, b128-aligned
__device__ __forceinline__ int fbt_addr(int col, int k) {
    return col * 512 + ((k * 2) ^ ((col & 31) << 4));
}
// LDS byte addr for HbT[col][k] (col<64, k<128, bf16) — overlays FbT region (base 0)
__device__ __forceinline__ int hbt_addr(int col, int k) {
    return col * 256 + ((k * 2) ^ ((col & 7) << 4));
}

// Pack W1 (128x256) and W2 (65x128 -> 80x128 zero-pad) into MFMA A-fragment order,
// fragment index = ks*NM + m (ks-major: 8KB window shared by the 4 waves via L1).
// A-frag for 16x16x32: lane l holds A[m*16 + (l&15)][ks*32 + (l>>4)*8 + j], j=0..7.
__global__ __launch_bounds__(256) void prep_weights(
    const float* __restrict__ W1, const float* __restrict__ W2,
    const float* __restrict__ b2, float* __restrict__ ws)
{
    int t = blockIdx.x * 256 + threadIdx.x;
    unsigned short* W1a = (unsigned short*)(ws + WS_W1A_F);
    unsigned short* W2a = (unsigned short*)(ws + WS_W2A_F);
    if (t < 32768) {
        int j = t & 7, l = (t >> 3) & 63, f = t >> 9;   // f = ks*8 + m
        int ks = f >> 3, m = f & 7;
        int row = m * 16 + (l & 15);
        int k   = ks * 32 + (l >> 4) * 8 + j;
        W1a[t] = f2bf(W1[row * CIN + k]);
    } else if (t < 32768 + 10240) {
        int u = t - 32768;
        int j = u & 7, l = (u >> 3) & 63, f = u >> 9;   // f = ks*5 + m
        int ks = f / 5, m = f % 5;
        int row = m * 16 + (l & 15);
        int k   = ks * 32 + (l >> 4) * 8 + j;
        W2a[u] = f2bf(row < 65 ? W2[row * HID + k] : 0.0f);
    } else if (t < 32768 + 10240 + 80) {
        int v = t - 43008;
        ws[WS_B2P + v] = (v < 65) ? b2[v] : 0.0f;
    }
}

// One block = 64 spatial positions of one batch b.
__global__ __launch_bounds__(256, 4) void conv_mfma(
    const float* __restrict__ features, const float* __restrict__ grid,
    const float* __restrict__ anc,      const float* __restrict__ b1,
    const float* __restrict__ bboxes,
    float* __restrict__ ws,             float* __restrict__ dout)
{
    __shared__ __align__(16) char smem[32768];   // FbT 32KB; HbT(16KB)/Ot(20.8KB) overlay

    const int tid = threadIdx.x;
    const int s0  = blockIdx.x * 64;
    const int b   = s0 >> 12;
    const int hw0 = s0 & (HW - 1);
    const int col = tid & 63;
    const int wv  = tid >> 6;          // wave id 0..3
    const int ln  = tid & 63;
    const int kg  = ln >> 4;           // k-group 0..3
    const int colg = wv * 16 + (ln & 15);

    // ---- stage F tile (256 x 64): float4 loads (1KB/wave-instr) + in-register
    // 4x4 lane transpose (shfl_xor 32/16 butterfly) -> bf16 -> swizzled FbT ----
    {
        const int g = ln >> 4, q = ln & 15;
        const float* fb = features + (size_t)b * CIN * HW + hw0;
        #pragma unroll
        for (int i = 0; i < 16; ++i) {
            const int k = i * 16 + wv * 4 + g;                     // 4 rows/instr
            const float4 v = *(const float4*)(fb + (size_t)k * HW + 4 * q);
            // stage A: partner g^2 (lane^32) — swap 2x2 blocks
            float t0 = __shfl_xor(v.x, 32), t1 = __shfl_xor(v.y, 32);
            float t2 = __shfl_xor(v.z, 32), t3 = __shfl_xor(v.w, 32);
            const bool h2 = (g & 2) != 0;
            float p0 = h2 ? t2 : v.x, p1 = h2 ? t3 : v.y;
            float p2 = h2 ? v.z : t0, p3 = h2 ? v.w : t1;
            // stage B: partner g^1 (lane^16) — transpose within 2x2 blocks
            float u0 = __shfl_xor(p0, 16), u1 = __shfl_xor(p1, 16);
            float u2 = __shfl_xor(p2, 16), u3 = __shfl_xor(p3, 16);
            const bool h1 = (g & 1) != 0;
            float c0 = h1 ? u1 : p0, c1 = h1 ? p1 : u0;
            float c2 = h1 ? u3 : p2, c3 = h1 ? p3 : u2;
            // lane now holds col = 4q+g, rows k0..k0+3
            const int k0 = i * 16 + wv * 4;
            uint2 pk;
            pk.x = (unsigned)f2bf(c0) | ((unsigned)f2bf(c1) << 16);
            pk.y = (unsigned)f2bf(c2) | ((unsigned)f2bf(c3) << 16);
            *(uint2*)(smem + fbt_addr(4 * q + g, k0)) = pk;
        }
    }
    __syncthreads();

    // ---- GEMM1: hdn[128][64] = W1 @ F ----
    const unsigned short* W1a = (const unsigned short*)(ws + WS_W1A_F);
    f32x4 acc[8];
    #pragma unroll
    for (int m = 0; m < 8; ++m) acc[m] = (f32x4){0.f, 0.f, 0.f, 0.f};
    #pragma unroll
    for (int ks = 0; ks < 8; ++ks) {
        short8 bf = *(const short8*)(smem + fbt_addr(colg, ks * 32 + kg * 8));
        #pragma unroll
        for (int m = 0; m < 8; ++m) {
            short8 af = *(const short8*)(W1a + ((ks * 8 + m) * 64 + ln) * 8);
            acc[m] = __builtin_amdgcn_mfma_f32_16x16x32_bf16(af, bf, acc[m], 0, 0, 0);
        }
    }
    __syncthreads();   // all FbT reads done before HbT overlays the region

    // ---- bias + leaky relu, bf16, write HbT (swizzled, overlays FbT) ----
    #pragma unroll
    for (int m = 0; m < 8; ++m) {
        float4 bv = *(const float4*)(b1 + m * 16 + kg * 4);
        float v0 = acc[m][0] + bv.x, v1 = acc[m][1] + bv.y;
        float v2 = acc[m][2] + bv.z, v3 = acc[m][3] + bv.w;
        v0 = v0 > 0.f ? v0 : 0.01f * v0;  v1 = v1 > 0.f ? v1 : 0.01f * v1;
        v2 = v2 > 0.f ? v2 : 0.01f * v2;  v3 = v3 > 0.f ? v3 : 0.01f * v3;
        unsigned int lo = (unsigned int)f2bf(v0) | ((unsigned int)f2bf(v1) << 16);
        unsigned int hi = (unsigned int)f2bf(v2) | ((unsigned int)f2bf(v3) << 16);
        *(uint2*)(smem + hbt_addr(colg, m * 16 + kg * 4)) = make_uint2(lo, hi);
    }
    __syncthreads();

    // ---- GEMM2: out[80][64] = W2pad @ hdn ----
    const unsigned short* W2a = (const unsigned short*)(ws + WS_W2A_F);
    f32x4 a2[5];
    #pragma unroll
    for (int m = 0; m < 5; ++m) a2[m] = (f32x4){0.f, 0.f, 0.f, 0.f};
    #pragma unroll
    for (int ks = 0; ks < 4; ++ks) {
        short8 bf = *(const short8*)(smem + hbt_addr(colg, ks * 32 + kg * 8));
        #pragma unroll
        for (int m = 0; m < 5; ++m) {
            short8 af = *(const short8*)(W2a + ((ks * 5 + m) * 64 + ln) * 8);
            a2[m] = __builtin_amdgcn_mfma_f32_16x16x32_bf16(af, bf, a2[m], 0, 0, 0);
        }
    }

    // ---- fused IoU: lane = (hwi 0..3, nq 0..15); 4 boxes/lane -> f32x4 NT stores.
    {
        const int hwi = ln >> 4;
        const int nq  = ln & 15;
        float bx0[4], by0[4], bx2[4], by2[4], areab[4];
        #pragma unroll
        for (int j = 0; j < 4; ++j) {
            const float* bb = bboxes + ((size_t)b * NBOX + nq * 4 + j) * 5;
            bx0[j] = bb[0]; by0[j] = bb[1]; bx2[j] = bb[2]; by2[j] = bb[3];
            areab[j] = (bx2[j] - bx0[j]) * (by2[j] - by0[j]);
        }
        const float2* gp = (const float2*)grid + (size_t)b * HW;
        float* ioub = dout + IOU_OFF + (size_t)b * A_ * HW * NBOX;
        for (int t = 0; t < 4; ++t) {
            int hw = hw0 + wv * 16 + t * 4 + hwi;
            float2 g = gp[hw];
            float e2x[4], e0x[4], e2y[4], e0y[4];
            #pragma unroll
            for (int j = 0; j < 4; ++j) {
                e2x[j] = bx2[j] - g.x;  e0x[j] = bx0[j] - g.x;
                e2y[j] = by2[j] - g.y;  e0y[j] = by0[j] - g.y;
            }
            #pragma unroll
            for (int a = 0; a < A_; ++a) {
                float hwd = 0.5f * anc[2 * a], hh = 0.5f * anc[2 * a + 1];
                float ap  = 4.0f * hwd * hh;
                f32x4 res;
                #pragma unroll
                for (int j = 0; j < 4; ++j) {
                    float dx = fmaxf(fminf(e2x[j], hwd) - fmaxf(e0x[j], -hwd), 0.0f);
                    float dy = fmaxf(fminf(e2y[j], hh ) - fmaxf(e0y[j], -hh ), 0.0f);
                    float inter = dx * dy;
                    res[j] = inter * vrcp(ap + areab[j] - inter);
                }
                __builtin_nontemporal_store(
                    res, (f32x4*)(ioub + ((size_t)a * HW + hw) * NBOX + nq * 4));
            }
        }
    }
    __syncthreads();   // all HbT reads done before Ot overlays the region

    // ---- stage out tile to LDS (fp32, stride 65) ----
    float* Ot = (float*)smem;
    const float* b2p = ws + WS_B2P;
    #pragma unroll
    for (int m = 0; m < 5; ++m) {
        float4 bv = *(const float4*)(b2p + m * 16 + kg * 4);
        #pragma unroll
        for (int i = 0; i < 4; ++i)
            Ot[(m * 16 + kg * 4 + i) * 65 + colg] = a2[m][i] + ((const float*)&bv)[i];
    }
    __syncthreads();

    // ---- epilogue: wave 0 conf, waves 1-2 offsets+proposals, wave 3 cls ----
    const float* OtC = (const float*)smem;
    const int hw = hw0 + col;
    if (wv == 0) {
        #pragma unroll
        for (int a = 0; a < A_; ++a)
            ws[WS_CONF + (size_t)(b * A_ + a) * HW + hw] = OtC[a * 65 + col];
    } else if (wv == 3) {
        #pragma unroll
        for (int c = 0; c < NCLS; ++c)
            ws[WS_CLS + (size_t)c * S_TOT + b * HW + hw] = OtC[(45 + c) * 65 + col];
    } else {
        const float2 g2 = ((const float2*)grid)[(size_t)b * HW + hw];
        int a0 = (wv == 1) ? 0 : 4;
        int a1 = (wv == 1) ? 4 : 9;
        for (int a = a0; a < a1; ++a) {
            float t0 = OtC[(A_ + 4 * a + 0) * 65 + col];
            float t1 = OtC[(A_ + 4 * a + 1) * 65 + col];
            float t2 = OtC[(A_ + 4 * a + 2) * 65 + col];
            float t3 = OtC[(A_ + 4 * a + 3) * 65 + col];
            t0 = fsig(t0) - 0.5f;
            t1 = fsig(t1) - 0.5f;
            size_t idx = (size_t)(b * A_ + a) * HW + hw;
            ((float4*)(ws + WS_OFF4))[idx] = make_float4(t0, t1, t2, t3);
            float aw = anc[2 * a], ah = anc[2 * a + 1];
            float xc = g2.x + t0, yc = g2.y + t1;
            float wn = aw * fexp(t2), hn = ah * fexp(t3);
            f32x4 prop = {xc - 0.5f * wn, yc - 0.5f * hn,
                          xc + 0.5f * wn, yc + 0.5f * hn};
            __builtin_nontemporal_store(prop, (f32x4*)dout + idx);
        }
    }
}

// blocks [0,320): class_scores gather; block 320: conf+reg losses.
__global__ __launch_bounds__(256) void tail_kernel(
    const float* __restrict__ ws, const float* __restrict__ GT_offsets,
    const int* __restrict__ pos_idx, const int* __restrict__ neg_idx,
    float* __restrict__ dout)
{
    int tid = threadIdx.x;
    if (blockIdx.x < 320) {
        int t = blockIdx.x * 256 + tid;            // 81920 = 320*256 exactly
        int m = t / NCLS, c = t % NCLS;
        int ip = pos_idx[m];
        int bb = ip / (A_ * HW);
        int hw = ip & (HW - 1);
        dout[CLS_OFF + t] = ws[WS_CLS + (size_t)c * S_TOT + bb * HW + hw];
        return;
    }
    float conf_sum = 0.0f, reg_sum = 0.0f;
    for (int m = tid; m < M_; m += 256) {
        int ip = pos_idx[m], in_ = neg_idx[m];
        float cp = fsig(ws[WS_CONF + ip]);
        float cn = fsig(ws[WS_CONF + in_]);
        conf_sum += (cp - 1.0f) * (cp - 1.0f) + cn * cn;
        float4 off = ((const float4*)(ws + WS_OFF4))[ip];
        float d0 = off.x - GT_offsets[4 * m + 0];
        float d1 = off.y - GT_offsets[4 * m + 1];
        float d2 = off.z - GT_offsets[4 * m + 2];
        float d3 = off.w - GT_offsets[4 * m + 3];
        reg_sum += d0 * d0 + d1 * d1 + d2 * d2 + d3 * d3;
    }
    #pragma unroll
    for (int off = 32; off > 0; off >>= 1) {
        conf_sum += __shfl_down(conf_sum, off);
        reg_sum  += __shfl_down(reg_sum, off);
    }
    __shared__ float rc[4], rr[4];
    int w = tid >> 6;
    if ((tid & 63) == 0) { rc[w] = conf_sum; rr[w] = reg_sum; }
    __syncthreads();
    if (tid == 0) {
        float c = rc[0] + rc[1] + rc[2] + rc[3];
        float r = rr[0] + rr[1] + rr[2] + rr[3];
        dout[CONF_LOSS_OFF] = c / (2.0f * M_);
        dout[REG_LOSS_OFF]  = r / (float)M_;
    }
}

extern "C" void kernel_launch(void* const* d_in, const int* in_sizes, int n_in,
                              void* d_out, int out_size, void* d_ws, size_t ws_size,
                              hipStream_t stream) {
    const float* features    = (const float*)d_in[0];
    const float* grid        = (const float*)d_in[1];
    const float* anc         = (const float*)d_in[2];
    const float* bboxes      = (const float*)d_in[3];
    const float* GT_offsets  = (const float*)d_in[4];
    const float* W1          = (const float*)d_in[6];
    const float* b1          = (const float*)d_in[7];
    const float* W2          = (const float*)d_in[8];
    const float* b2          = (const float*)d_in[9];
    const int*   pos_idx     = (const int*)d_in[10];
    const int*   neg_idx     = (const int*)d_in[11];
    float* out = (float*)d_out;
    float* ws  = (float*)d_ws;

    prep_weights<<<169, 256, 0, stream>>>(W1, W2, b2, ws);
    conv_mfma<<<S_TOT / 64, 256, 0, stream>>>(features, grid, anc, b1, bboxes, ws, out);
    tail_kernel<<<321, 256, 0, stream>>>(ws, GT_offsets, pos_idx, neg_idx, out);
}

// Round 7
// 115.656 us; speedup vs baseline: 6.0005x; 1.0266x over previous
//
#include <hip/hip_runtime.h>
#include <math.h>

typedef __attribute__((ext_vector_type(8))) short short8;
typedef __attribute__((ext_vector_type(4))) float f32x4;

#define HW    4096
#define B_    32
#define CIN   256
#define HID   128
#define A_    9
#define NCLS  20
#define M_    4096
#define NBOX  64
#define S_TOT (B_*HW)

// ---- output layout (floats) ----
#define PROP_SIZE (B_*A_*HW*4)
#define IOU_OFF   ((size_t)PROP_SIZE)
#define IOU_SIZE  ((size_t)B_*A_*HW*NBOX)
#define CONF_LOSS_OFF (IOU_OFF + IOU_SIZE)
#define REG_LOSS_OFF  (CONF_LOSS_OFF + 1)
#define CLS_OFF       (CONF_LOSS_OFF + 2)

// ---- workspace layout (float offsets) ----
#define WS_W1A_F 0                          // 32768 ushort (W1, A-frag order [ks][m])
#define WS_W2A_F 16384                      // 10240 ushort (W2 padded to 80 rows, [ks][m])
#define WS_B2P   21504                      // 80 floats (b2 padded)
#define WS_CONF  21632                      // B*A*HW raw conf
#define WS_OFF4  (WS_CONF + B_*A_*HW)       // B*A*HW float4 offsets
#define WS_CLS   (WS_OFF4 + B_*A_*HW*4)     // 20 planes of B*HW raw class scores

__device__ __forceinline__ unsigned short f2bf(float x) {   // RNE float->bf16
    unsigned int u = __float_as_uint(x);
    unsigned int r = (u + 0x7FFFu + ((u >> 16) & 1u)) >> 16;
    return (unsigned short)r;
}
__device__ __forceinline__ float vrcp(float x) {            // v_rcp_f32, ~1ulp
    float r; asm("v_rcp_f32 %0, %1" : "=v"(r) : "v"(x)); return r;
}
__device__ __forceinline__ float vexp2(float x) {           // v_exp_f32 = 2^x
    float r; asm("v_exp_f32 %0, %1" : "=v"(r) : "v"(x)); return r;
}
__device__ __forceinline__ float fexp(float x)  { return vexp2(x * 1.44269504f); }
__device__ __forceinline__ float fsig(float x)  { return vrcp(1.0f + fexp(-x)); }

// LDS byte addr for FbT[col][k] (col<64, k<256, bf16), XOR-swizzled, b128-aligned
__device__ __forceinline__ int fbt_addr(int col, int k) {
    return col * 512 + ((k * 2) ^ ((col & 31) << 4));
}
// LDS byte addr for HbT[col][k] (col<64, k<128, bf16) — overlays FbT region (base 0)
__device__ __forceinline__ int hbt_addr(int col, int k) {
    return col * 256 + ((k * 2) ^ ((col & 7) << 4));
}

// Pack W1 (128x256) and W2 (65x128 -> 80x128 zero-pad) into MFMA A-fragment order,
// fragment index = ks*NM + m (ks-major: 8KB window shared by the waves via L1).
// A-frag for 16x16x32: lane l holds A[m*16 + (l&15)][ks*32 + (l>>4)*8 + j], j=0..7.
__global__ __launch_bounds__(256) void prep_weights(
    const float* __restrict__ W1, const float* __restrict__ W2,
    const float* __restrict__ b2, float* __restrict__ ws)
{
    int t = blockIdx.x * 256 + threadIdx.x;
    unsigned short* W1a = (unsigned short*)(ws + WS_W1A_F);
    unsigned short* W2a = (unsigned short*)(ws + WS_W2A_F);
    if (t < 32768) {
        int j = t & 7, l = (t >> 3) & 63, f = t >> 9;   // f = ks*8 + m
        int ks = f >> 3, m = f & 7;
        int row = m * 16 + (l & 15);
        int k   = ks * 32 + (l >> 4) * 8 + j;
        W1a[t] = f2bf(W1[row * CIN + k]);
    } else if (t < 32768 + 10240) {
        int u = t - 32768;
        int j = u & 7, l = (u >> 3) & 63, f = u >> 9;   // f = ks*5 + m
        int ks = f / 5, m = f % 5;
        int row = m * 16 + (l & 15);
        int k   = ks * 32 + (l >> 4) * 8 + j;
        W2a[u] = f2bf(row < 65 ? W2[row * HID + k] : 0.0f);
    } else if (t < 32768 + 10240 + 80) {
        int v = t - 43008;
        ws[WS_B2P + v] = (v < 65) ? b2[v] : 0.0f;
    }
}

// One block = 64 spatial positions of one batch b. 8 waves:
//   all 8 stage F; waves 0-3: GEMM1 -> HbT -> GEMM2 -> Ot -> epilogue;
//   waves 4-7: IoU in 4 chunks interleaved with the same 5 barriers
//   (MFMA/LDS pipe and VALU/store pipe run concurrently; m114 overlap).
__global__ __launch_bounds__(512, 4) void conv_mfma(
    const float* __restrict__ features, const float* __restrict__ grid,
    const float* __restrict__ anc,      const float* __restrict__ b1,
    const float* __restrict__ bboxes,
    float* __restrict__ ws,             float* __restrict__ dout)
{
    __shared__ __align__(16) char smem[32768];   // FbT 32KB; HbT(16KB)/Ot(20.8KB) overlay

    const int tid = threadIdx.x;
    const int s0  = blockIdx.x * 64;
    const int b   = s0 >> 12;
    const int hw0 = s0 & (HW - 1);
    const int col = tid & 63;
    const int wv  = tid >> 6;          // wave id 0..7
    const int ln  = tid & 63;
    const int kg  = ln >> 4;           // k-group 0..3

    // ---- stage F tile (256 x 64), ALL 8 waves: float4 loads + in-register
    // 4x4 lane transpose (shfl_xor 32/16 butterfly) -> bf16 -> swizzled FbT ----
    {
        const int g = ln >> 4, q = ln & 15;
        const float* fb = features + (size_t)b * CIN * HW + hw0;
        #pragma unroll
        for (int i = 0; i < 8; ++i) {
            const int k = i * 32 + wv * 4 + g;                     // 4 rows/instr
            const float4 v = *(const float4*)(fb + (size_t)k * HW + 4 * q);
            // stage A: partner g^2 (lane^32) — swap 2x2 blocks
            float t0 = __shfl_xor(v.x, 32), t1 = __shfl_xor(v.y, 32);
            float t2 = __shfl_xor(v.z, 32), t3 = __shfl_xor(v.w, 32);
            const bool h2 = (g & 2) != 0;
            float p0 = h2 ? t2 : v.x, p1 = h2 ? t3 : v.y;
            float p2 = h2 ? v.z : t0, p3 = h2 ? v.w : t1;
            // stage B: partner g^1 (lane^16) — transpose within 2x2 blocks
            float u0 = __shfl_xor(p0, 16), u1 = __shfl_xor(p1, 16);
            float u2 = __shfl_xor(p2, 16), u3 = __shfl_xor(p3, 16);
            const bool h1 = (g & 1) != 0;
            float c0 = h1 ? u1 : p0, c1 = h1 ? p1 : u0;
            float c2 = h1 ? u3 : p2, c3 = h1 ? p3 : u2;
            // lane now holds col = 4q+g, rows k0..k0+3
            const int k0 = i * 32 + wv * 4;
            uint2 pk;
            pk.x = (unsigned)f2bf(c0) | ((unsigned)f2bf(c1) << 16);
            pk.y = (unsigned)f2bf(c2) | ((unsigned)f2bf(c3) << 16);
            *(uint2*)(smem + fbt_addr(4 * q + g, k0)) = pk;
        }
    }
    __syncthreads();                                   // B1

    if (wv < 4) {
        const int colg = wv * 16 + (ln & 15);

        // ---- GEMM1: hdn[128][64] = W1 @ F ----
        const unsigned short* W1a = (const unsigned short*)(ws + WS_W1A_F);
        f32x4 acc[8];
        #pragma unroll
        for (int m = 0; m < 8; ++m) acc[m] = (f32x4){0.f, 0.f, 0.f, 0.f};
        #pragma unroll
        for (int ks = 0; ks < 8; ++ks) {
            short8 bf = *(const short8*)(smem + fbt_addr(colg, ks * 32 + kg * 8));
            #pragma unroll
            for (int m = 0; m < 8; ++m) {
                short8 af = *(const short8*)(W1a + ((ks * 8 + m) * 64 + ln) * 8);
                acc[m] = __builtin_amdgcn_mfma_f32_16x16x32_bf16(af, bf, acc[m], 0, 0, 0);
            }
        }
        __syncthreads();                               // B2 (FbT reads done)

        // ---- bias + leaky relu, bf16, write HbT (swizzled, overlays FbT) ----
        #pragma unroll
        for (int m = 0; m < 8; ++m) {
            float4 bv = *(const float4*)(b1 + m * 16 + kg * 4);
            float v0 = acc[m][0] + bv.x, v1 = acc[m][1] + bv.y;
            float v2 = acc[m][2] + bv.z, v3 = acc[m][3] + bv.w;
            v0 = v0 > 0.f ? v0 : 0.01f * v0;  v1 = v1 > 0.f ? v1 : 0.01f * v1;
            v2 = v2 > 0.f ? v2 : 0.01f * v2;  v3 = v3 > 0.f ? v3 : 0.01f * v3;
            unsigned int lo = (unsigned int)f2bf(v0) | ((unsigned int)f2bf(v1) << 16);
            unsigned int hi = (unsigned int)f2bf(v2) | ((unsigned int)f2bf(v3) << 16);
            *(uint2*)(smem + hbt_addr(colg, m * 16 + kg * 4)) = make_uint2(lo, hi);
        }
        __syncthreads();                               // B3

        // ---- GEMM2: out[80][64] = W2pad @ hdn ----
        const unsigned short* W2a = (const unsigned short*)(ws + WS_W2A_F);
        f32x4 a2[5];
        #pragma unroll
        for (int m = 0; m < 5; ++m) a2[m] = (f32x4){0.f, 0.f, 0.f, 0.f};
        #pragma unroll
        for (int ks = 0; ks < 4; ++ks) {
            short8 bf = *(const short8*)(smem + hbt_addr(colg, ks * 32 + kg * 8));
            #pragma unroll
            for (int m = 0; m < 5; ++m) {
                short8 af = *(const short8*)(W2a + ((ks * 5 + m) * 64 + ln) * 8);
                a2[m] = __builtin_amdgcn_mfma_f32_16x16x32_bf16(af, bf, a2[m], 0, 0, 0);
            }
        }
        __syncthreads();                               // B4 (HbT reads done)

        // ---- stage out tile to LDS (fp32, stride 65, overlays) ----
        float* Ot = (float*)smem;
        const float* b2p = ws + WS_B2P;
        #pragma unroll
        for (int m = 0; m < 5; ++m) {
            float4 bv = *(const float4*)(b2p + m * 16 + kg * 4);
            #pragma unroll
            for (int i = 0; i < 4; ++i)
                Ot[(m * 16 + kg * 4 + i) * 65 + colg] = a2[m][i] + ((const float*)&bv)[i];
        }
        __syncthreads();                               // B5

        // ---- epilogue: wave 0 conf, waves 1-2 offsets+proposals, wave 3 cls ----
        const float* OtC = (const float*)smem;
        const int hw = hw0 + col;
        if (wv == 0) {
            #pragma unroll
            for (int a = 0; a < A_; ++a)
                ws[WS_CONF + (size_t)(b * A_ + a) * HW + hw] = OtC[a * 65 + col];
        } else if (wv == 3) {
            #pragma unroll
            for (int c = 0; c < NCLS; ++c)
                ws[WS_CLS + (size_t)c * S_TOT + b * HW + hw] = OtC[(45 + c) * 65 + col];
        } else {
            const float2 g2 = ((const float2*)grid)[(size_t)b * HW + hw];
            int a0 = (wv == 1) ? 0 : 4;
            int a1 = (wv == 1) ? 4 : 9;
            for (int a = a0; a < a1; ++a) {
                float t0 = OtC[(A_ + 4 * a + 0) * 65 + col];
                float t1 = OtC[(A_ + 4 * a + 1) * 65 + col];
                float t2 = OtC[(A_ + 4 * a + 2) * 65 + col];
                float t3 = OtC[(A_ + 4 * a + 3) * 65 + col];
                t0 = fsig(t0) - 0.5f;
                t1 = fsig(t1) - 0.5f;
                size_t idx = (size_t)(b * A_ + a) * HW + hw;
                ((float4*)(ws + WS_OFF4))[idx] = make_float4(t0, t1, t2, t3);
                float aw = anc[2 * a], ah = anc[2 * a + 1];
                float xc = g2.x + t0, yc = g2.y + t1;
                float wn = aw * fexp(t2), hn = ah * fexp(t3);
                f32x4 prop = {xc - 0.5f * wn, yc - 0.5f * hn,
                              xc + 0.5f * wn, yc + 0.5f * hn};
                __builtin_nontemporal_store(prop, (f32x4*)dout + idx);
            }
        }
    } else {
        // ---- IoU waves: wave wi owns 16 hw rows; lane = (hwi 0..3, nq 0..15);
        // 4 boxes/lane -> f32x4 NT stores. One t-chunk per barrier interval.
        const int wi  = wv - 4;
        const int hwi = ln >> 4;
        const int nq  = ln & 15;
        float bx0[4], by0[4], bx2[4], by2[4], areab[4];
        #pragma unroll
        for (int j = 0; j < 4; ++j) {
            const float* bb = bboxes + ((size_t)b * NBOX + nq * 4 + j) * 5;
            bx0[j] = bb[0]; by0[j] = bb[1]; bx2[j] = bb[2]; by2[j] = bb[3];
            areab[j] = (bx2[j] - bx0[j]) * (by2[j] - by0[j]);
        }
        const float2* gp = (const float2*)grid + (size_t)b * HW;
        float* ioub = dout + IOU_OFF + (size_t)b * A_ * HW * NBOX;
        #pragma unroll
        for (int t = 0; t < 4; ++t) {
            int hw = hw0 + wi * 16 + t * 4 + hwi;
            float2 g = gp[hw];
            float e2x[4], e0x[4], e2y[4], e0y[4];
            #pragma unroll
            for (int j = 0; j < 4; ++j) {
                e2x[j] = bx2[j] - g.x;  e0x[j] = bx0[j] - g.x;
                e2y[j] = by2[j] - g.y;  e0y[j] = by0[j] - g.y;
            }
            #pragma unroll
            for (int a = 0; a < A_; ++a) {
                float hwd = 0.5f * anc[2 * a], hh = 0.5f * anc[2 * a + 1];
                float ap  = 4.0f * hwd * hh;
                f32x4 res;
                #pragma unroll
                for (int j = 0; j < 4; ++j) {
                    float dx = fmaxf(fminf(e2x[j], hwd) - fmaxf(e0x[j], -hwd), 0.0f);
                    float dy = fmaxf(fminf(e2y[j], hh ) - fmaxf(e0y[j], -hh ), 0.0f);
                    float inter = dx * dy;
                    res[j] = inter * vrcp(ap + areab[j] - inter);
                }
                __builtin_nontemporal_store(
                    res, (f32x4*)(ioub + ((size_t)a * HW + hw) * NBOX + nq * 4));
            }
            __syncthreads();                           // B2..B5
        }
        // exits having executed B1 + 4 barriers = 5, matching the GEMM path
    }
}

// blocks [0,320): class_scores gather; block 320: conf+reg losses.
__global__ __launch_bounds__(256) void tail_kernel(
    const float* __restrict__ ws, const float* __restrict__ GT_offsets,
    const int* __restrict__ pos_idx, const int* __restrict__ neg_idx,
    float* __restrict__ dout)
{
    int tid = threadIdx.x;
    if (blockIdx.x < 320) {
        int t = blockIdx.x * 256 + tid;            // 81920 = 320*256 exactly
        int m = t / NCLS, c = t % NCLS;
        int ip = pos_idx[m];
        int bb = ip / (A_ * HW);
        int hw = ip & (HW - 1);
        dout[CLS_OFF + t] = ws[WS_CLS + (size_t)c * S_TOT + bb * HW + hw];
        return;
    }
    float conf_sum = 0.0f, reg_sum = 0.0f;
    for (int m = tid; m < M_; m += 256) {
        int ip = pos_idx[m], in_ = neg_idx[m];
        float cp = fsig(ws[WS_CONF + ip]);
        float cn = fsig(ws[WS_CONF + in_]);
        conf_sum += (cp - 1.0f) * (cp - 1.0f) + cn * cn;
        float4 off = ((const float4*)(ws + WS_OFF4))[ip];
        float d0 = off.x - GT_offsets[4 * m + 0];
        float d1 = off.y - GT_offsets[4 * m + 1];
        float d2 = off.z - GT_offsets[4 * m + 2];
        float d3 = off.w - GT_offsets[4 * m + 3];
        reg_sum += d0 * d0 + d1 * d1 + d2 * d2 + d3 * d3;
    }
    #pragma unroll
    for (int off = 32; off > 0; off >>= 1) {
        conf_sum += __shfl_down(conf_sum, off);
        reg_sum  += __shfl_down(reg_sum, off);
    }
    __shared__ float rc[4], rr[4];
    int w = tid >> 6;
    if ((tid & 63) == 0) { rc[w] = conf_sum; rr[w] = reg_sum; }
    __syncthreads();
    if (tid == 0) {
        float c = rc[0] + rc[1] + rc[2] + rc[3];
        float r = rr[0] + rr[1] + rr[2] + rr[3];
        dout[CONF_LOSS_OFF] = c / (2.0f * M_);
        dout[REG_LOSS_OFF]  = r / (float)M_;
    }
}

extern "C" void kernel_launch(void* const* d_in, const int* in_sizes, int n_in,
                              void* d_out, int out_size, void* d_ws, size_t ws_size,
                              hipStream_t stream) {
    const float* features    = (const float*)d_in[0];
    const float* grid        = (const float*)d_in[1];
    const float* anc         = (const float*)d_in[2];
    const float* bboxes      = (const float*)d_in[3];
    const float* GT_offsets  = (const float*)d_in[4];
    const float* W1          = (const float*)d_in[6];
    const float* b1          = (const float*)d_in[7];
    const float* W2          = (const float*)d_in[8];
    const float* b2          = (const float*)d_in[9];
    const int*   pos_idx     = (const int*)d_in[10];
    const int*   neg_idx     = (const int*)d_in[11];
    float* out = (float*)d_out;
    float* ws  = (float*)d_ws;

    prep_weights<<<169, 256, 0, stream>>>(W1, W2, b2, ws);
    conv_mfma<<<S_TOT / 64, 512, 0, stream>>>(features, grid, anc, b1, bboxes, ws, out);
    tail_kernel<<<321, 256, 0, stream>>>(ws, GT_offsets, pos_idx, neg_idx, out);
}

// Round 8
// 108.622 us; speedup vs baseline: 6.3890x; 1.0648x over previous
//
#include <hip/hip_runtime.h>
#include <math.h>

typedef __attribute__((ext_vector_type(8))) short short8;
typedef __attribute__((ext_vector_type(4))) float f32x4;

#define HW    4096
#define B_    32
#define CIN   256
#define HID   128
#define A_    9
#define NCLS  20
#define M_    4096
#define NBOX  64
#define S_TOT (B_*HW)

// ---- output layout (floats) ----
#define PROP_SIZE (B_*A_*HW*4)
#define IOU_OFF   ((size_t)PROP_SIZE)
#define IOU_SIZE  ((size_t)B_*A_*HW*NBOX)
#define CONF_LOSS_OFF (IOU_OFF + IOU_SIZE)
#define REG_LOSS_OFF  (CONF_LOSS_OFF + 1)
#define CLS_OFF       (CONF_LOSS_OFF + 2)

// ---- workspace layout (float offsets) ----
#define WS_W1A_F 0                          // 32768 ushort (W1, A-frag order [ks][m])
#define WS_W2A_F 16384                      // 10240 ushort (W2 padded to 80 rows, [ks][m])
#define WS_B2P   21504                      // 80 floats (b2 padded)
#define WS_CONF  21632                      // B*A*HW raw conf
#define WS_OFF4  (WS_CONF + B_*A_*HW)       // B*A*HW float4 offsets
#define WS_CLS   (WS_OFF4 + B_*A_*HW*4)     // 20 planes of B*HW raw class scores

#define NCONV 2048
#define NIOU  2304                          // 9216 wave-chunks / 4 waves
#define NBLK  (NCONV + NIOU)                // 4352

__device__ __forceinline__ unsigned short f2bf(float x) {   // RNE float->bf16
    unsigned int u = __float_as_uint(x);
    unsigned int r = (u + 0x7FFFu + ((u >> 16) & 1u)) >> 16;
    return (unsigned short)r;
}
__device__ __forceinline__ float vrcp(float x) {            // v_rcp_f32, ~1ulp
    float r; asm("v_rcp_f32 %0, %1" : "=v"(r) : "v"(x)); return r;
}
__device__ __forceinline__ float vexp2(float x) {           // v_exp_f32 = 2^x
    float r; asm("v_exp_f32 %0, %1" : "=v"(r) : "v"(x)); return r;
}
__device__ __forceinline__ float fexp(float x)  { return vexp2(x * 1.44269504f); }
__device__ __forceinline__ float fsig(float x)  { return vrcp(1.0f + fexp(-x)); }

// LDS byte addr for FbT[col][k] (col<64, k<256, bf16), XOR-swizzled, b128-aligned
__device__ __forceinline__ int fbt_addr(int col, int k) {
    return col * 512 + ((k * 2) ^ ((col & 31) << 4));
}
// LDS byte addr for HbT[col][k] (col<64, k<128, bf16) — overlays FbT region (base 0)
__device__ __forceinline__ int hbt_addr(int col, int k) {
    return col * 256 + ((k * 2) ^ ((col & 7) << 4));
}

// Pack W1 (128x256) and W2 (65x128 -> 80x128 zero-pad) into MFMA A-fragment order,
// fragment index = ks*NM + m (ks-major: 8KB window shared by the waves via L1).
// A-frag for 16x16x32: lane l holds A[m*16 + (l&15)][ks*32 + (l>>4)*8 + j], j=0..7.
__global__ __launch_bounds__(256) void prep_weights(
    const float* __restrict__ W1, const float* __restrict__ W2,
    const float* __restrict__ b2, float* __restrict__ ws)
{
    int t = blockIdx.x * 256 + threadIdx.x;
    unsigned short* W1a = (unsigned short*)(ws + WS_W1A_F);
    unsigned short* W2a = (unsigned short*)(ws + WS_W2A_F);
    if (t < 32768) {
        int j = t & 7, l = (t >> 3) & 63, f = t >> 9;   // f = ks*8 + m
        int ks = f >> 3, m = f & 7;
        int row = m * 16 + (l & 15);
        int k   = ks * 32 + (l >> 4) * 8 + j;
        W1a[t] = f2bf(W1[row * CIN + k]);
    } else if (t < 32768 + 10240) {
        int u = t - 32768;
        int j = u & 7, l = (u >> 3) & 63, f = u >> 9;   // f = ks*5 + m
        int ks = f / 5, m = f % 5;
        int row = m * 16 + (l & 15);
        int k   = ks * 32 + (l >> 4) * 8 + j;
        W2a[u] = f2bf(row < 65 ? W2[row * HID + k] : 0.0f);
    } else if (t < 32768 + 10240 + 80) {
        int v = t - 43008;
        ws[WS_B2P + v] = (v < 65) ? b2[v] : 0.0f;
    }
}

// Role-split fused kernel: even bids<4096 = conv tile (64 spatial positions),
// odd bids + tail = IoU chunk blocks. No barriers couple the two roles; the
// IoU blocks' NT stores drain while conv blocks sit in staging/MFMA latency.
__global__ __launch_bounds__(256, 4) void fused_kernel(
    const float* __restrict__ features, const float* __restrict__ grid,
    const float* __restrict__ anc,      const float* __restrict__ b1,
    const float* __restrict__ bboxes,
    float* __restrict__ ws,             float* __restrict__ dout)
{
    const int bid = blockIdx.x;
    const int tid = threadIdx.x;
    const int wv  = tid >> 6;
    const int ln  = tid & 63;

    bool is_conv; int idx;
    if (bid < 2 * NCONV) { is_conv = (bid & 1) == 0; idx = bid >> 1; }
    else                 { is_conv = false;          idx = NCONV + (bid - 2 * NCONV); }

    if (!is_conv) {
        // ---- IoU block: 4 waves, wave = one (b, a, 128-hw) chunk ----
        const int cid = idx * 4 + wv;                 // 0..9215
        const int b   = cid / (A_ * 32);
        const int rem = cid % (A_ * 32);
        const int a   = rem / 32;
        const int hw0 = (rem % 32) * 128;
        const int hwi = ln >> 4;
        const int nq  = ln & 15;

        float bx0[4], by0[4], bx2[4], by2[4], areab[4];
        #pragma unroll
        for (int j = 0; j < 4; ++j) {
            const float* bb = bboxes + ((size_t)b * NBOX + nq * 4 + j) * 5;
            bx0[j] = bb[0]; by0[j] = bb[1]; bx2[j] = bb[2]; by2[j] = bb[3];
            areab[j] = (bx2[j] - bx0[j]) * (by2[j] - by0[j]);
        }
        const float hwd = 0.5f * anc[2 * a], hh = 0.5f * anc[2 * a + 1];
        const float ap  = 4.0f * hwd * hh;
        const float2* gp = (const float2*)grid + (size_t)b * HW;
        float* ioub = dout + IOU_OFF + (size_t)(b * A_ + a) * HW * NBOX;
        #pragma unroll 4
        for (int t = 0; t < 32; ++t) {
            const int hw = hw0 + t * 4 + hwi;
            const float2 g = gp[hw];
            f32x4 res;
            #pragma unroll
            for (int j = 0; j < 4; ++j) {
                float dx = fmaxf(fminf(bx2[j] - g.x, hwd) - fmaxf(bx0[j] - g.x, -hwd), 0.0f);
                float dy = fmaxf(fminf(by2[j] - g.y, hh ) - fmaxf(by0[j] - g.y, -hh ), 0.0f);
                float inter = dx * dy;
                res[j] = inter * vrcp(ap + areab[j] - inter);
            }
            // wave store = 1KB contiguous (addr = base + ln*16)
            __builtin_nontemporal_store(
                res, (f32x4*)(ioub + ((size_t)hw) * NBOX + nq * 4));
        }
        return;
    }

    // ---- conv block ----
    __shared__ __align__(16) char smem[32768];   // FbT 32KB; HbT/Ot overlay

    const int s0  = idx * 64;
    const int b   = s0 >> 12;
    const int hw0 = s0 & (HW - 1);
    const int col = tid & 63;
    const int kg  = ln >> 4;           // k-group 0..3
    const int colg = wv * 16 + (ln & 15);

    // ---- stage F tile (256 x 64): float4 loads + in-register 4x4 lane
    // transpose (shfl_xor 32/16 butterfly) -> bf16 -> swizzled FbT ----
    {
        const int g = ln >> 4, q = ln & 15;
        const float* fb = features + (size_t)b * CIN * HW + hw0;
        #pragma unroll
        for (int i = 0; i < 16; ++i) {
            const int k = i * 16 + wv * 4 + g;                     // 4 rows/instr
            const float4 v = *(const float4*)(fb + (size_t)k * HW + 4 * q);
            float t0 = __shfl_xor(v.x, 32), t1 = __shfl_xor(v.y, 32);
            float t2 = __shfl_xor(v.z, 32), t3 = __shfl_xor(v.w, 32);
            const bool h2 = (g & 2) != 0;
            float p0 = h2 ? t2 : v.x, p1 = h2 ? t3 : v.y;
            float p2 = h2 ? v.z : t0, p3 = h2 ? v.w : t1;
            float u0 = __shfl_xor(p0, 16), u1 = __shfl_xor(p1, 16);
            float u2 = __shfl_xor(p2, 16), u3 = __shfl_xor(p3, 16);
            const bool h1 = (g & 1) != 0;
            float c0 = h1 ? u1 : p0, c1 = h1 ? p1 : u0;
            float c2 = h1 ? u3 : p2, c3 = h1 ? p3 : u2;
            const int k0 = i * 16 + wv * 4;
            uint2 pk;
            pk.x = (unsigned)f2bf(c0) | ((unsigned)f2bf(c1) << 16);
            pk.y = (unsigned)f2bf(c2) | ((unsigned)f2bf(c3) << 16);
            *(uint2*)(smem + fbt_addr(4 * q + g, k0)) = pk;
        }
    }
    __syncthreads();

    // ---- GEMM1: hdn[128][64] = W1 @ F ----
    const unsigned short* W1a = (const unsigned short*)(ws + WS_W1A_F);
    f32x4 acc[8];
    #pragma unroll
    for (int m = 0; m < 8; ++m) acc[m] = (f32x4){0.f, 0.f, 0.f, 0.f};
    #pragma unroll
    for (int ks = 0; ks < 8; ++ks) {
        short8 bf = *(const short8*)(smem + fbt_addr(colg, ks * 32 + kg * 8));
        #pragma unroll
        for (int m = 0; m < 8; ++m) {
            short8 af = *(const short8*)(W1a + ((ks * 8 + m) * 64 + ln) * 8);
            acc[m] = __builtin_amdgcn_mfma_f32_16x16x32_bf16(af, bf, acc[m], 0, 0, 0);
        }
    }
    __syncthreads();   // all FbT reads done before HbT overlays the region

    // ---- bias + leaky relu, bf16, write HbT (swizzled, overlays FbT) ----
    #pragma unroll
    for (int m = 0; m < 8; ++m) {
        float4 bv = *(const float4*)(b1 + m * 16 + kg * 4);
        float v0 = acc[m][0] + bv.x, v1 = acc[m][1] + bv.y;
        float v2 = acc[m][2] + bv.z, v3 = acc[m][3] + bv.w;
        v0 = v0 > 0.f ? v0 : 0.01f * v0;  v1 = v1 > 0.f ? v1 : 0.01f * v1;
        v2 = v2 > 0.f ? v2 : 0.01f * v2;  v3 = v3 > 0.f ? v3 : 0.01f * v3;
        unsigned int lo = (unsigned int)f2bf(v0) | ((unsigned int)f2bf(v1) << 16);
        unsigned int hi = (unsigned int)f2bf(v2) | ((unsigned int)f2bf(v3) << 16);
        *(uint2*)(smem + hbt_addr(colg, m * 16 + kg * 4)) = make_uint2(lo, hi);
    }
    __syncthreads();

    // ---- GEMM2: out[80][64] = W2pad @ hdn ----
    const unsigned short* W2a = (const unsigned short*)(ws + WS_W2A_F);
    f32x4 a2[5];
    #pragma unroll
    for (int m = 0; m < 5; ++m) a2[m] = (f32x4){0.f, 0.f, 0.f, 0.f};
    #pragma unroll
    for (int ks = 0; ks < 4; ++ks) {
        short8 bf = *(const short8*)(smem + hbt_addr(colg, ks * 32 + kg * 8));
        #pragma unroll
        for (int m = 0; m < 5; ++m) {
            short8 af = *(const short8*)(W2a + ((ks * 5 + m) * 64 + ln) * 8);
            a2[m] = __builtin_amdgcn_mfma_f32_16x16x32_bf16(af, bf, a2[m], 0, 0, 0);
        }
    }
    __syncthreads();   // all HbT reads done before Ot overlays the region

    // ---- stage out tile to LDS (fp32, stride 65) ----
    float* Ot = (float*)smem;
    const float* b2p = ws + WS_B2P;
    #pragma unroll
    for (int m = 0; m < 5; ++m) {
        float4 bv = *(const float4*)(b2p + m * 16 + kg * 4);
        #pragma unroll
        for (int i = 0; i < 4; ++i)
            Ot[(m * 16 + kg * 4 + i) * 65 + colg] = a2[m][i] + ((const float*)&bv)[i];
    }
    __syncthreads();

    // ---- epilogue: wave 0 conf, waves 1-2 offsets+proposals, wave 3 cls ----
    const float* OtC = (const float*)smem;
    const int hw = hw0 + col;
    if (wv == 0) {
        #pragma unroll
        for (int a = 0; a < A_; ++a)
            ws[WS_CONF + (size_t)(b * A_ + a) * HW + hw] = OtC[a * 65 + col];
    } else if (wv == 3) {
        #pragma unroll
        for (int c = 0; c < NCLS; ++c)
            ws[WS_CLS + (size_t)c * S_TOT + b * HW + hw] = OtC[(45 + c) * 65 + col];
    } else {
        const float2 g2 = ((const float2*)grid)[(size_t)b * HW + hw];
        int a0 = (wv == 1) ? 0 : 4;
        int a1 = (wv == 1) ? 4 : 9;
        for (int a = a0; a < a1; ++a) {
            float t0 = OtC[(A_ + 4 * a + 0) * 65 + col];
            float t1 = OtC[(A_ + 4 * a + 1) * 65 + col];
            float t2 = OtC[(A_ + 4 * a + 2) * 65 + col];
            float t3 = OtC[(A_ + 4 * a + 3) * 65 + col];
            t0 = fsig(t0) - 0.5f;
            t1 = fsig(t1) - 0.5f;
            size_t odx = (size_t)(b * A_ + a) * HW + hw;
            ((float4*)(ws + WS_OFF4))[odx] = make_float4(t0, t1, t2, t3);
            float aw = anc[2 * a], ah = anc[2 * a + 1];
            float xc = g2.x + t0, yc = g2.y + t1;
            float wn = aw * fexp(t2), hn = ah * fexp(t3);
            f32x4 prop = {xc - 0.5f * wn, yc - 0.5f * hn,
                          xc + 0.5f * wn, yc + 0.5f * hn};
            __builtin_nontemporal_store(prop, (f32x4*)dout + odx);
        }
    }
}

// blocks [0,320): class_scores gather; block 320: conf+reg losses.
__global__ __launch_bounds__(256) void tail_kernel(
    const float* __restrict__ ws, const float* __restrict__ GT_offsets,
    const int* __restrict__ pos_idx, const int* __restrict__ neg_idx,
    float* __restrict__ dout)
{
    int tid = threadIdx.x;
    if (blockIdx.x < 320) {
        int t = blockIdx.x * 256 + tid;            // 81920 = 320*256 exactly
        int m = t / NCLS, c = t % NCLS;
        int ip = pos_idx[m];
        int bb = ip / (A_ * HW);
        int hw = ip & (HW - 1);
        dout[CLS_OFF + t] = ws[WS_CLS + (size_t)c * S_TOT + bb * HW + hw];
        return;
    }
    float conf_sum = 0.0f, reg_sum = 0.0f;
    for (int m = tid; m < M_; m += 256) {
        int ip = pos_idx[m], in_ = neg_idx[m];
        float cp = fsig(ws[WS_CONF + ip]);
        float cn = fsig(ws[WS_CONF + in_]);
        conf_sum += (cp - 1.0f) * (cp - 1.0f) + cn * cn;
        float4 off = ((const float4*)(ws + WS_OFF4))[ip];
        float d0 = off.x - GT_offsets[4 * m + 0];
        float d1 = off.y - GT_offsets[4 * m + 1];
        float d2 = off.z - GT_offsets[4 * m + 2];
        float d3 = off.w - GT_offsets[4 * m + 3];
        reg_sum += d0 * d0 + d1 * d1 + d2 * d2 + d3 * d3;
    }
    #pragma unroll
    for (int off = 32; off > 0; off >>= 1) {
        conf_sum += __shfl_down(conf_sum, off);
        reg_sum  += __shfl_down(reg_sum, off);
    }
    __shared__ float rc[4], rr[4];
    int w = tid >> 6;
    if ((tid & 63) == 0) { rc[w] = conf_sum; rr[w] = reg_sum; }
    __syncthreads();
    if (tid == 0) {
        float c = rc[0] + rc[1] + rc[2] + rc[3];
        float r = rr[0] + rr[1] + rr[2] + rr[3];
        dout[CONF_LOSS_OFF] = c / (2.0f * M_);
        dout[REG_LOSS_OFF]  = r / (float)M_;
    }
}

extern "C" void kernel_launch(void* const* d_in, const int* in_sizes, int n_in,
                              void* d_out, int out_size, void* d_ws, size_t ws_size,
                              hipStream_t stream) {
    const float* features    = (const float*)d_in[0];
    const float* grid        = (const float*)d_in[1];
    const float* anc         = (const float*)d_in[2];
    const float* bboxes      = (const float*)d_in[3];
    const float* GT_offsets  = (const float*)d_in[4];
    const float* W1          = (const float*)d_in[6];
    const float* b1          = (const float*)d_in[7];
    const float* W2          = (const float*)d_in[8];
    const float* b2          = (const float*)d_in[9];
    const int*   pos_idx     = (const int*)d_in[10];
    const int*   neg_idx     = (const int*)d_in[11];
    float* out = (float*)d_out;
    float* ws  = (float*)d_ws;

    prep_weights<<<169, 256, 0, stream>>>(W1, W2, b2, ws);
    fused_kernel<<<NBLK, 256, 0, stream>>>(features, grid, anc, b1, bboxes, ws, out);
    tail_kernel<<<321, 256, 0, stream>>>(ws, GT_offsets, pos_idx, neg_idx, out);
}